// Round 3
// baseline (1401.896 us; speedup 1.0000x reference)
//
#include <hip/hip_runtime.h>
#include <hip/hip_cooperative_groups.h>
#include <math.h>

namespace cg = cooperative_groups;

#define LEN   5440
#define NB    2
#define MROWS (NB * LEN)   // 10880
#define DM    256
#define NH    8
#define HD    32
#define NLV   4
#define NPT   4
#define DFFN  1024

typedef __attribute__((ext_vector_type(8))) short bf16x8;
typedef __attribute__((ext_vector_type(4))) short bf16x4;
typedef __attribute__((ext_vector_type(4))) float f32x4;

#define MFMA16 __builtin_amdgcn_mfma_f32_16x16x32_bf16

__device__ __forceinline__ short f2bf(float f) {
    union { float f; unsigned u; } cv; cv.f = f;
    unsigned r = cv.u + 0x7fffu + ((cv.u >> 16) & 1u);   // RNE
    return (short)(r >> 16);
}
__device__ __forceinline__ float bf2f(short s) {
    union { unsigned u; float f; } cv;
    cv.u = ((unsigned)(unsigned short)s) << 16;
    return cv.f;
}

__device__ __forceinline__ void gload16(const short* g, short* l) {
    __builtin_amdgcn_global_load_lds(
        (__attribute__((address_space(1))) void*)g,
        (__attribute__((address_space(3))) void*)l, 16, 0, 0);
}

template <int N> __device__ __forceinline__ void vmwait();
template <> __device__ __forceinline__ void vmwait<0>() { asm volatile("s_waitcnt vmcnt(0)" ::: "memory"); }
template <> __device__ __forceinline__ void vmwait<4>() { asm volatile("s_waitcnt vmcnt(4)" ::: "memory"); }
template <> __device__ __forceinline__ void vmwait<5>() { asm volatile("s_waitcnt vmcnt(5)" ::: "memory"); }

// chunk swizzle within a 64B row (4 x 16B chunks): phys = logical ^ swz(row).
__device__ __forceinline__ int swz(int row) { return (row >> 1) & 3; }

// ---------------------------------------------------------------------------
// Parameter block (single kernel arg for all paths).
// ---------------------------------------------------------------------------
struct KParams {
    const float *Wv, *Woff, *Wa, *Wo, *Wl1, *Wl2;
    const float4 *s4, *p4;
    const float *vr, *pos;
    const float *bv, *boff, *ba, *bo, *g1, *be1, *bl1, *bl2, *g2, *be2;
    float *OFF, *AW;
    short *Vb, *curb, *qb, *ATTb, *XAb, *FFNb, *Wt;
    float *out;
};

// ---------------------------------------------------------------------------
// prep unit: t in [0,1472) -> weight transpose tile; [1472,4192) -> src convert.
// ---------------------------------------------------------------------------
__device__ __forceinline__ void prep_unit(int t, const KParams& P, short* T)
{
    if (t >= 1472) {
        const int i = (t - 1472) * 256 + threadIdx.x;
        float4 s = P.s4[i], p = P.p4[i];
        bf16x4 c, q;
        c[0] = f2bf(s.x); c[1] = f2bf(s.y); c[2] = f2bf(s.z); c[3] = f2bf(s.w);
        q[0] = f2bf(s.x + p.x); q[1] = f2bf(s.y + p.y);
        q[2] = f2bf(s.z + p.z); q[3] = f2bf(s.w + p.w);
        ((bf16x4*)P.curb)[i] = c; ((bf16x4*)P.qb)[i] = q;
        return;
    }
    __syncthreads();                      // WAR guard for T across loop iters
    int l = t / 736;
    int u = t % 736;
    const float* src; int K, N; long doff;
    if      (u < 64)  { src = P.Wv;   K = 256;  N = 256;  doff = 0;      }
    else if (u < 128) { src = P.Woff; K = 256;  N = 256;  doff = 65536;  u -= 64;  }
    else if (u < 160) { src = P.Wa;   K = 256;  N = 128;  doff = 131072; u -= 128; }
    else if (u < 224) { src = P.Wo;   K = 256;  N = 256;  doff = 163840; u -= 160; }
    else if (u < 480) { src = P.Wl1;  K = 256;  N = 1024; doff = 229376; u -= 224; }
    else              { src = P.Wl2;  K = 1024; N = 256;  doff = 491520; u -= 480; }
    src += (long)l * K * N;
    short* dst = P.Wt + (long)l * 753664 + doff;

    const int ntx = N / 32;
    const int n0 = (u % ntx) * 32, k0 = (u / ntx) * 32;
    const int tid = threadIdx.x;
    {
        const int n = tid & 31, kq = tid >> 5;
        #pragma unroll
        for (int i = 0; i < 4; ++i) {
            int k = kq * 4 + i;
            T[n * 33 + k] = f2bf(src[(long)(k0 + k) * N + n0 + n]);
        }
    }
    __syncthreads();
    {
        const int k = tid & 31, nq = tid >> 5;
        #pragma unroll
        for (int i = 0; i < 4; ++i) {
            int n = nq * 4 + i;
            dst[(long)(n0 + n) * K + k0 + k] = T[n * 33 + k];
        }
    }
}

// ---------------------------------------------------------------------------
// 128x128 GEMM tile, BK=32, gload_lds 2-buffer counted-vmcnt (R1 structure).
// smem: As @0 (16KB), Bs @16384 (16KB).
// OMODE: 0 f32 row-major, 1 bf16 row-major, 2 bf16 into V planes.
// ---------------------------------------------------------------------------
template <int RELU, int OMODE, int K>
__device__ __forceinline__ void gemm_tile_v2(
    char* smem, const short* __restrict__ A, const short* __restrict__ Wt,
    const float* __restrict__ bias, float* __restrict__ Cf,
    short* __restrict__ Cb, int ldc, int m0, int wrow0, int ccol0)
{
    constexpr int NT = K / 32;
    static_assert(NT >= 4 && (NT & 1) == 0, "NT even >= 4");
    short* As = (short*)smem;
    short* Bs = (short*)(smem + 16384);

    const int t    = threadIdx.x;
    const int wave = t >> 6, lane = t & 63;
    const int wm   = (wave & 1) * 64;
    const int wn   = (wave >> 1) * 64;
    const int lm   = lane & 15;
    const int chkg = lane >> 4;

    const short* aS[2]; const short* bS[2];
    short *aD[2], *bD[2];
    #pragma unroll
    for (int i = 0; i < 2; ++i) {
        const int c   = wave * 2 + i;
        const int row = c * 16 + (lane >> 2);
        const int xc  = (lane & 3) ^ swz(row);
        aS[i] = A  + (long)(m0 + row) * K + xc * 8;
        bS[i] = Wt + (long)(wrow0 + row) * K + xc * 8;
        aD[i] = As + c * 512;
        bD[i] = Bs + c * 512;
    }

    int offA[4], offB[4];
    #pragma unroll
    for (int s = 0; s < 4; ++s) {
        const int r = wm + s * 16 + lm;
        offA[s] = r * 32 + (chkg ^ swz(r)) * 8;
    }
    #pragma unroll
    for (int u = 0; u < 4; ++u) {
        const int r = wn + u * 16 + lm;
        offB[u] = r * 32 + (chkg ^ swz(r)) * 8;
    }

    f32x4 acc[4][4] = {};

#define STG128(BUF, KT) do {                                          \
        const int _ko = (KT) * 32;                                    \
        gload16(aS[0] + _ko, aD[0] + (BUF) * 4096);                   \
        gload16(bS[0] + _ko, bD[0] + (BUF) * 4096);                   \
        gload16(aS[1] + _ko, aD[1] + (BUF) * 4096);                   \
        gload16(bS[1] + _ko, bD[1] + (BUF) * 4096);                   \
    } while (0)

#define GB128(T, BUF, WN, DOSTAGE) do {                               \
        vmwait<WN>();                                                 \
        __builtin_amdgcn_s_barrier();                                 \
        bf16x8 af[4], bv[4];                                          \
        _Pragma("unroll")                                             \
        for (int s = 0; s < 4; ++s)                                   \
            af[s] = *(const bf16x8*)(As + (BUF) * 4096 + offA[s]);    \
        _Pragma("unroll")                                             \
        for (int u = 0; u < 4; ++u)                                   \
            bv[u] = *(const bf16x8*)(Bs + (BUF) * 4096 + offB[u]);    \
        asm volatile("s_waitcnt lgkmcnt(0)" ::: "memory");            \
        __builtin_amdgcn_s_barrier();                                 \
        __builtin_amdgcn_sched_barrier(0);                            \
        if (DOSTAGE) STG128(BUF, (T) + 2);                            \
        _Pragma("unroll")                                             \
        for (int s = 0; s < 4; ++s)                                   \
            _Pragma("unroll")                                         \
            for (int u = 0; u < 4; ++u)                               \
                acc[s][u] = MFMA16(af[s], bv[u], acc[s][u], 0, 0, 0); \
    } while (0)

    STG128(0, 0);
    STG128(1, 1);
    for (int tt = 0; tt < NT - 2; tt += 2) {
        GB128(tt,     0, 4, true);
        GB128(tt + 1, 1, 4, true);
    }
    GB128(NT - 2, 0, 4, false);
    GB128(NT - 1, 1, 0, false);
#undef GB128
#undef STG128

    const int col = lane & 15;
    const int rq  = (lane >> 4) * 4;
    #pragma unroll
    for (int s = 0; s < 4; ++s) {
        #pragma unroll
        for (int u = 0; u < 4; ++u) {
            const int gn = ccol0 + wn + u * 16 + col;
            const float bb = bias[gn];
            #pragma unroll
            for (int r = 0; r < 4; ++r) {
                const int gm = m0 + wm + s * 16 + rq + r;
                float v = acc[s][u][r] + bb;
                if (RELU) v = fmaxf(v, 0.f);
                if (OMODE == 0) {
                    Cf[(long)gm * ldc + gn] = v;
                } else if (OMODE == 1) {
                    Cb[(long)gm * ldc + gn] = f2bf(v);
                } else {
                    const int n   = gm / LEN;
                    const int pix = gm - n * LEN;
                    const int h   = gn >> 5, d = gn & 31;
                    Cb[((long)(n * NH + h) * LEN + pix) * 32 + d] = f2bf(v);
                }
            }
        }
    }
}

// qkv tile dispatcher: w in [0,425): n0=(w%5)*128, m0=(w/5)*128.
__device__ __forceinline__ void qkv_tile(
    char* smem, int w, const KParams& P, const short* Wb,
    const float* bv, const float* boff, const float* ba)
{
    const int n0 = (w % 5) * 128, m0 = (w / 5) * 128;
    if (n0 < 256) {
        gemm_tile_v2<0, 2, 256>(smem, P.curb, Wb, bv, (float*)nullptr, P.Vb,
                                256, m0, n0, n0);
    } else if (n0 < 512) {
        gemm_tile_v2<0, 0, 256>(smem, P.qb, Wb, boff, P.OFF, (short*)nullptr,
                                256, m0, n0, n0 - 256);
    } else {
        gemm_tile_v2<0, 0, 256>(smem, P.qb, Wb, ba, P.AW, (short*)nullptr,
                                128, m0, n0, n0 - 512);
    }
}

// ---------------------------------------------------------------------------
// Fused GEMM + residual + LayerNorm tile (M=32, N=256), R1 structure.
// smem: As @0 (4KB), Bs @4096 (32KB), red @36864 (512B).
// ---------------------------------------------------------------------------
template <int K>
__device__ __forceinline__ void ln_tile_v2(
    char* smem, const short* __restrict__ A, const short* __restrict__ Wt,
    const float* __restrict__ bias, const short* __restrict__ residb,
    const float* __restrict__ g, const float* __restrict__ be,
    short* __restrict__ outb, short* __restrict__ outq,
    float* __restrict__ outf, const float* __restrict__ pos, int m0)
{
    constexpr int NT = K / 32;
    short* As = (short*)smem;
    short* Bs = (short*)(smem + 4096);
    float (*red)[32][2] = (float (*)[32][2])(smem + 36864);

    const int t    = threadIdx.x;
    const int wave = t >> 6, lane = t & 63;
    const int wm   = (wave & 1) * 16;
    const int wn   = (wave >> 1) * 128;
    const int lm   = lane & 15;
    const int chkg = lane >> 4;
    const int rq   = chkg * 4;
    const bool hasA = (wave & 1) == 0;

    short rr[8][4];
    #pragma unroll
    for (int u = 0; u < 8; ++u)
        #pragma unroll
        for (int r = 0; r < 4; ++r)
            rr[u][r] = residb[(long)(m0 + wm + rq + r) * DM + wn + u * 16 + lm];
    asm volatile("" ::: "memory");

    const short* bSp[4]; short* bDp[4];
    #pragma unroll
    for (int i = 0; i < 4; ++i) {
        const int c   = wave * 4 + i;
        const int row = c * 16 + (lane >> 2);
        const int xc  = (lane & 3) ^ swz(row);
        bSp[i] = Wt + (long)row * K + xc * 8;
        bDp[i] = Bs + c * 512;
    }
    const short* aSp = nullptr; short* aDp = nullptr;
    if (hasA) {
        const int c   = wave >> 1;
        const int row = c * 16 + (lane >> 2);
        const int xc  = (lane & 3) ^ swz(row);
        aSp = A + (long)(m0 + row) * K + xc * 8;
        aDp = As + c * 512;
    }

    const int offA = (wm + lm) * 32 + (chkg ^ swz(wm + lm)) * 8;
    int offB[8];
    #pragma unroll
    for (int u = 0; u < 8; ++u) {
        const int r = wn + u * 16 + lm;
        offB[u] = r * 32 + (chkg ^ swz(r)) * 8;
    }

    f32x4 acc[8] = {};

#define STGL(BUF, KT) do {                                            \
        const int _ko = (KT) * 32;                                    \
        if (hasA) gload16(aSp + _ko, aDp + (BUF) * 1024);             \
        gload16(bSp[0] + _ko, bDp[0] + (BUF) * 8192);                 \
        gload16(bSp[1] + _ko, bDp[1] + (BUF) * 8192);                 \
        gload16(bSp[2] + _ko, bDp[2] + (BUF) * 8192);                 \
        gload16(bSp[3] + _ko, bDp[3] + (BUF) * 8192);                 \
    } while (0)

#define GBLN(T, BUF, WA, WB, DOSTAGE) do {                            \
        if (hasA) vmwait<WA>(); else vmwait<WB>();                    \
        __builtin_amdgcn_s_barrier();                                 \
        bf16x8 af = *(const bf16x8*)(As + (BUF) * 1024 + offA);       \
        bf16x8 bv[8];                                                 \
        _Pragma("unroll")                                             \
        for (int u = 0; u < 8; ++u)                                   \
            bv[u] = *(const bf16x8*)(Bs + (BUF) * 8192 + offB[u]);    \
        asm volatile("s_waitcnt lgkmcnt(0)" ::: "memory");            \
        __builtin_amdgcn_s_barrier();                                 \
        __builtin_amdgcn_sched_barrier(0);                            \
        if (DOSTAGE) STGL(BUF, (T) + 2);                              \
        _Pragma("unroll")                                             \
        for (int u = 0; u < 8; ++u)                                   \
            acc[u] = MFMA16(af, bv[u], acc[u], 0, 0, 0);              \
    } while (0)

    STGL(0, 0);
    STGL(1, 1);
    for (int tt = 0; tt < NT - 2; tt += 2) {
        GBLN(tt,     0, 5, 4, true);
        GBLN(tt + 1, 1, 5, 4, true);
    }
    GBLN(NT - 2, 0, 5, 4, false);
    GBLN(NT - 1, 1, 0, 0, false);
#undef GBLN
#undef STGL

    #pragma unroll
    for (int u = 0; u < 8; ++u) {
        const int gn = wn + u * 16 + lm;
        const float bb = bias[gn];
        #pragma unroll
        for (int r = 0; r < 4; ++r)
            acc[u][r] += bb + bf2f(rr[u][r]);
    }

    float rs[4], r2[4];
    #pragma unroll
    for (int r = 0; r < 4; ++r) {
        float s = 0.f, s2 = 0.f;
        #pragma unroll
        for (int u = 0; u < 8; ++u) { const float v = acc[u][r]; s += v; s2 += v * v; }
        rs[r] = s; r2[r] = s2;
    }
    #pragma unroll
    for (int o = 1; o < 16; o <<= 1)
        #pragma unroll
        for (int r = 0; r < 4; ++r) {
            rs[r] += __shfl_xor(rs[r], o, 64);
            r2[r] += __shfl_xor(r2[r], o, 64);
        }
    if (lm == 0) {
        #pragma unroll
        for (int r = 0; r < 4; ++r) {
            red[wave >> 1][wm + rq + r][0] = rs[r];
            red[wave >> 1][wm + rq + r][1] = r2[r];
        }
    }
    __syncthreads();
    #pragma unroll
    for (int r = 0; r < 4; ++r) {
        const int row = wm + rq + r;
        const float ts = red[0][row][0] + red[1][row][0];
        const float t2 = red[0][row][1] + red[1][row][1];
        const float mean = ts * (1.f / DM);
        const float var  = t2 * (1.f / DM) - mean * mean;
        rs[r] = mean;
        r2[r] = rsqrtf(var + 1e-5f);
    }
    #pragma unroll
    for (int u = 0; u < 8; ++u) {
        const int gn = wn + u * 16 + lm;
        const float gg = g[gn], bbe = be[gn];
        #pragma unroll
        for (int r = 0; r < 4; ++r) {
            const long gm = m0 + wm + rq + r;
            const float o = (acc[u][r] - rs[r]) * r2[r] * gg + bbe;
            if (outb) outb[gm * DM + gn] = f2bf(o);
            if (outq) outq[gm * DM + gn] = f2bf(o + pos[gm * DM + gn]);
            if (outf) outf[gm * DM + gn] = o;
        }
    }
}

// ---------------------------------------------------------------------------
// Deformable attention sampling unit (bx in [0,2720)).
// ---------------------------------------------------------------------------
__device__ __forceinline__ void deform_unit(
    int bx, const short* __restrict__ Vb, const float* __restrict__ OFF,
    const float* __restrict__ AW, const float* __restrict__ vr,
    bf16x4* __restrict__ ATTb)
{
    const int starts[5] = {0, 4096, 5120, 5376, 5440};
    const int dims[4]   = {64, 32, 16, 8};

    const int wave = threadIdx.x >> 6;
    const int lane = threadIdx.x & 63;
    const int h    = lane >> 3;
    const int d4   = lane & 7;

    const int gq = bx * 4 + wave;
    const int n  = gq / LEN;
    const int q  = gq % LEN;

    int lq = 3;
    if (q < 4096) lq = 0; else if (q < 5120) lq = 1; else if (q < 5376) lq = 2;
    const int r  = q - starts[lq];
    const int Wq = dims[lq];
    const int gy = r / Wq, gx = r % Wq;
    const float vrxq = vr[(n * NLV + lq) * 2 + 0];
    const float vryq = vr[(n * NLV + lq) * 2 + 1];
    const float rx = (gx + 0.5f) / (vrxq * Wq);
    const float ry = (gy + 0.5f) / (vryq * Wq);

    const long row = (long)n * LEN + q;

    const float* awp = AW + row * 128 + h * 16;
    float a[16];
    float mx = -1e30f;
    #pragma unroll
    for (int i = 0; i < 16; ++i) { a[i] = awp[i]; mx = fmaxf(mx, a[i]); }
    float s = 0.f;
    #pragma unroll
    for (int i = 0; i < 16; ++i) { a[i] = __expf(a[i] - mx); s += a[i]; }
    const float inv = 1.f / s;

    const float* offp = OFF + row * 256 + h * 32;

    float4 acc = {0.f, 0.f, 0.f, 0.f};
    #pragma unroll
    for (int lvl = 0; lvl < NLV; ++lvl) {
        const int Hl = dims[lvl];
        const int Wl = Hl;
        const float fW = (float)Wl;
        const int sb = starts[lvl];
        const float lx = rx * vr[(n * NLV + lvl) * 2 + 0];
        const float ly = ry * vr[(n * NLV + lvl) * 2 + 1];
        const short* vb = Vb + ((long)(n * NH + h) * LEN + sb) * 32 + d4 * 4;
        #pragma unroll
        for (int p = 0; p < NPT; ++p) {
            const float ox = offp[lvl * 8 + p * 2 + 0];
            const float oy = offp[lvl * 8 + p * 2 + 1];
            const float x = fmaf(lx, fW, ox) - 0.5f;
            const float y = fmaf(ly, fW, oy) - 0.5f;
            const float x0f = floorf(x), y0f = floorf(y);
            const int ix0 = (int)x0f, iy0 = (int)y0f;
            const float wx1 = x - x0f, wy1 = y - y0f;
            const float wx0 = 1.f - wx1, wy0 = 1.f - wy1;

            const bool vx0 = (ix0 >= 0)     && (ix0 < Wl);
            const bool vx1 = (ix0 + 1 >= 0) && (ix0 + 1 < Wl);
            const bool vy0 = (iy0 >= 0)     && (iy0 < Hl);
            const bool vy1 = (iy0 + 1 >= 0) && (iy0 + 1 < Hl);
            const int cx0 = min(max(ix0, 0), Wl - 1);
            const int cx1 = min(max(ix0 + 1, 0), Wl - 1);
            const int cy0 = min(max(iy0, 0), Hl - 1);
            const int cy1 = min(max(iy0 + 1, 0), Hl - 1);

            const float w00 = (vx0 && vy0) ? wx0 * wy0 : 0.f;
            const float w10 = (vx1 && vy0) ? wx1 * wy0 : 0.f;
            const float w01 = (vx0 && vy1) ? wx0 * wy1 : 0.f;
            const float w11 = (vx1 && vy1) ? wx1 * wy1 : 0.f;

            const bf16x4 g00 = *(const bf16x4*)(vb + (long)(cy0 * Wl + cx0) * 32);
            const bf16x4 g10 = *(const bf16x4*)(vb + (long)(cy0 * Wl + cx1) * 32);
            const bf16x4 g01 = *(const bf16x4*)(vb + (long)(cy1 * Wl + cx0) * 32);
            const bf16x4 g11 = *(const bf16x4*)(vb + (long)(cy1 * Wl + cx1) * 32);

            const float awv = a[lvl * 4 + p] * inv;
            #pragma unroll
            for (int e = 0; e < 4; ++e) {
                float sv = w00 * bf2f(g00[e]) + w10 * bf2f(g10[e])
                         + w01 * bf2f(g01[e]) + w11 * bf2f(g11[e]);
                (&acc.x)[e] += awv * sv;
            }
        }
    }
    bf16x4 ob;
    ob[0] = f2bf(acc.x); ob[1] = f2bf(acc.y);
    ob[2] = f2bf(acc.z); ob[3] = f2bf(acc.w);
    ATTb[row * 64 + h * 8 + d4] = ob;
}

// ---------------------------------------------------------------------------
// Persistent cooperative mega-kernel: all 11 stages, one dispatch, 10 syncs.
// 768 blocks x 256 thr = 3 blocks/CU co-resident (launch_bounds(256,3)).
// ---------------------------------------------------------------------------
__global__ __launch_bounds__(256, 3) void mega(KParams P)
{
    __shared__ __align__(16) char smem[37888];
    cg::grid_group grid = cg::this_grid();
    const int gsz = (int)gridDim.x;

    for (int w = blockIdx.x; w < 4192; w += gsz)
        prep_unit(w, P, (short*)smem);
    grid.sync();

    for (int l = 0; l < 2; ++l) {
        const short* Wb   = P.Wt + (long)l * 753664;
        const float* bv   = P.bv   + (long)l * DM;
        const float* boff = P.boff + (long)l * 256;
        const float* ba   = P.ba   + (long)l * 128;
        const float* bo   = P.bo   + (long)l * DM;
        const float* g1   = P.g1   + (long)l * DM;
        const float* be1  = P.be1  + (long)l * DM;
        const float* bl1  = P.bl1  + (long)l * DFFN;
        const float* bl2  = P.bl2  + (long)l * DM;
        const float* g2   = P.g2   + (long)l * DM;
        const float* be2  = P.be2  + (long)l * DM;

        for (int w = blockIdx.x; w < 425; w += gsz)
            qkv_tile(smem, w, P, Wb, bv, boff, ba);
        grid.sync();

        for (int w = blockIdx.x; w < 2720; w += gsz)
            deform_unit(w, P.Vb, P.OFF, P.AW, P.vr, (bf16x4*)P.ATTb);
        grid.sync();

        for (int w = blockIdx.x; w < 340; w += gsz)
            ln_tile_v2<256>(smem, P.ATTb, Wb + 163840, bo, P.curb, g1, be1,
                            P.XAb, (short*)nullptr, (float*)nullptr,
                            (const float*)nullptr, w * 32);
        grid.sync();

        for (int w = blockIdx.x; w < 680; w += gsz) {
            const int n0 = (w % 8) * 128, m0 = (w / 8) * 128;
            gemm_tile_v2<1, 1, 256>(smem, P.XAb, Wb + 229376, bl1,
                                    (float*)nullptr, P.FFNb, 1024, m0, n0, n0);
        }
        grid.sync();

        if (l == 0) {
            for (int w = blockIdx.x; w < 340; w += gsz)
                ln_tile_v2<1024>(smem, P.FFNb, Wb + 491520, bl2, P.XAb, g2, be2,
                                 P.curb, P.qb, (float*)nullptr, P.pos, w * 32);
            grid.sync();
        } else {
            for (int w = blockIdx.x; w < 340; w += gsz)
                ln_tile_v2<1024>(smem, P.FFNb, Wb + 491520, bl2, P.XAb, g2, be2,
                                 (short*)nullptr, (short*)nullptr, P.out,
                                 (const float*)nullptr, w * 32);
        }
    }
}

// ---------------------------------------------------------------------------
// Fallback path: same device functions as 11 regular dispatches.
// ---------------------------------------------------------------------------
__global__ __launch_bounds__(256) void prep_k(KParams P)
{
    __shared__ __align__(16) short T[32 * 33];
    prep_unit(blockIdx.x, P, T);
}
__global__ __launch_bounds__(256) void qkv_k(KParams P, int l)
{
    __shared__ __align__(16) char smem[32768];
    qkv_tile(smem, blockIdx.x, P, P.Wt + (long)l * 753664,
             P.bv + (long)l * DM, P.boff + (long)l * 256, P.ba + (long)l * 128);
}
__global__ __launch_bounds__(256) void deform_k(KParams P)
{
    deform_unit(blockIdx.x, P.Vb, P.OFF, P.AW, P.vr, (bf16x4*)P.ATTb);
}
__global__ __launch_bounds__(256) void ln1_k(KParams P, int l)
{
    __shared__ __align__(16) char smem[37888];
    ln_tile_v2<256>(smem, P.ATTb, P.Wt + (long)l * 753664 + 163840,
                    P.bo + (long)l * DM, P.curb,
                    P.g1 + (long)l * DM, P.be1 + (long)l * DM,
                    P.XAb, (short*)nullptr, (float*)nullptr,
                    (const float*)nullptr, blockIdx.x * 32);
}
__global__ __launch_bounds__(256) void ffn1_k(KParams P, int l)
{
    __shared__ __align__(16) char smem[32768];
    const int w = blockIdx.x;
    const int n0 = (w % 8) * 128, m0 = (w / 8) * 128;
    gemm_tile_v2<1, 1, 256>(smem, P.XAb, P.Wt + (long)l * 753664 + 229376,
                            P.bl1 + (long)l * DFFN, (float*)nullptr, P.FFNb,
                            1024, m0, n0, n0);
}
__global__ __launch_bounds__(256) void ln2_k(KParams P, int l)
{
    __shared__ __align__(16) char smem[37888];
    if (l == 0)
        ln_tile_v2<1024>(smem, P.FFNb, P.Wt + 491520, P.bl2, P.XAb,
                         P.g2, P.be2, P.curb, P.qb, (float*)nullptr,
                         P.pos, blockIdx.x * 32);
    else
        ln_tile_v2<1024>(smem, P.FFNb, P.Wt + 753664 + 491520, P.bl2 + DM,
                         P.XAb, P.g2 + DM, P.be2 + DM,
                         (short*)nullptr, (short*)nullptr, P.out,
                         (const float*)nullptr, blockIdx.x * 32);
}

// ---------------------------------------------------------------------------
extern "C" void kernel_launch(void* const* d_in, const int* in_sizes, int n_in,
                              void* d_out, int out_size, void* d_ws, size_t ws_size,
                              hipStream_t stream)
{
    const long SZ = (long)MROWS * DM;        // 2,785,280 elements
    float* ws = (float*)d_ws;

    KParams P;
    P.s4   = (const float4*)d_in[0];
    P.p4   = (const float4*)d_in[1];
    P.pos  = (const float*)d_in[1];
    P.vr   = (const float*)d_in[2];
    P.Wv   = (const float*)d_in[3];
    P.bv   = (const float*)d_in[4];
    P.Woff = (const float*)d_in[5];
    P.boff = (const float*)d_in[6];
    P.Wa   = (const float*)d_in[7];
    P.ba   = (const float*)d_in[8];
    P.Wo   = (const float*)d_in[9];
    P.bo   = (const float*)d_in[10];
    P.g1   = (const float*)d_in[11];
    P.be1  = (const float*)d_in[12];
    P.Wl1  = (const float*)d_in[13];
    P.bl1  = (const float*)d_in[14];
    P.Wl2  = (const float*)d_in[15];
    P.bl2  = (const float*)d_in[16];
    P.g2   = (const float*)d_in[17];
    P.be2  = (const float*)d_in[18];

    P.OFF  = ws;
    P.AW   = P.OFF + SZ;
    P.Vb   = (short*)(P.AW + (long)MROWS * 128);
    P.curb = P.Vb   + SZ;
    P.qb   = P.curb + SZ;
    P.ATTb = P.qb   + SZ;
    P.XAb  = P.ATTb + SZ;
    P.FFNb = P.XAb  + SZ;
    P.Wt   = P.FFNb + (long)MROWS * DFFN;
    P.out  = (float*)d_out;

    void* args[] = { (void*)&P };
    hipError_t ce = hipLaunchCooperativeKernel((void*)mega, dim3(768), dim3(256),
                                               args, 0, stream);
    if (ce != hipSuccess) {
        const dim3 blk(256);
        hipLaunchKernelGGL(prep_k, dim3(4192), blk, 0, stream, P);
        for (int l = 0; l < 2; ++l) {
            hipLaunchKernelGGL(qkv_k,    dim3(425),  blk, 0, stream, P, l);
            hipLaunchKernelGGL(deform_k, dim3(2720), blk, 0, stream, P);
            hipLaunchKernelGGL(ln1_k,    dim3(340),  blk, 0, stream, P, l);
            hipLaunchKernelGGL(ffn1_k,   dim3(680),  blk, 0, stream, P, l);
            hipLaunchKernelGGL(ln2_k,    dim3(340),  blk, 0, stream, P, l);
        }
    }
}

// Round 4
// 412.363 us; speedup vs baseline: 3.3997x; 3.3997x over previous
//
#include <hip/hip_runtime.h>
#include <math.h>

#define LEN   5440
#define NB    2
#define MROWS (NB * LEN)   // 10880
#define DM    256
#define NH    8
#define HD    32
#define NLV   4
#define NPT   4
#define DFFN  1024

typedef __attribute__((ext_vector_type(8))) short bf16x8;
typedef __attribute__((ext_vector_type(4))) short bf16x4;
typedef __attribute__((ext_vector_type(4))) float f32x4;

#define MFMA16 __builtin_amdgcn_mfma_f32_16x16x32_bf16

__device__ __forceinline__ short f2bf(float f) {
    union { float f; unsigned u; } cv; cv.f = f;
    unsigned r = cv.u + 0x7fffu + ((cv.u >> 16) & 1u);   // RNE
    return (short)(r >> 16);
}
__device__ __forceinline__ float bf2f(short s) {
    union { unsigned u; float f; } cv;
    cv.u = ((unsigned)(unsigned short)s) << 16;
    return cv.f;
}

__device__ __forceinline__ void gload16(const short* g, short* l) {
    __builtin_amdgcn_global_load_lds(
        (__attribute__((address_space(1))) void*)g,
        (__attribute__((address_space(3))) void*)l, 16, 0, 0);
}

template <int N> __device__ __forceinline__ void vmwait();
template <> __device__ __forceinline__ void vmwait<0>() { asm volatile("s_waitcnt vmcnt(0)" ::: "memory"); }
template <> __device__ __forceinline__ void vmwait<2>() { asm volatile("s_waitcnt vmcnt(2)" ::: "memory"); }
template <> __device__ __forceinline__ void vmwait<3>() { asm volatile("s_waitcnt vmcnt(3)" ::: "memory"); }
template <> __device__ __forceinline__ void vmwait<4>() { asm volatile("s_waitcnt vmcnt(4)" ::: "memory"); }
template <> __device__ __forceinline__ void vmwait<5>() { asm volatile("s_waitcnt vmcnt(5)" ::: "memory"); }

// chunk swizzle within a 64B row (4 x 16B chunks): phys = logical ^ swz(row).
__device__ __forceinline__ int swz(int row) { return (row >> 1) & 3; }

// ---------------------------------------------------------------------------
struct KParams {
    const float *Wv, *Woff, *Wa, *Wo, *Wl1, *Wl2;
    const float4 *s4, *p4;
    const float *vr, *pos;
    const float *bv, *boff, *ba, *bo, *g1, *be1, *bl1, *bl2, *g2, *be2;
    float *OFF, *AW;
    short *Vb, *Vb1, *curb, *qb, *ATTb, *XAb, *FFNb, *Wt;
    float *out;
};

// ---------------------------------------------------------------------------
// prep unit: t in [0,1472) -> weight transpose tile; [1472,4192) -> src convert.
// ---------------------------------------------------------------------------
__device__ __forceinline__ void prep_unit(int t, const KParams& P, short* T)
{
    if (t >= 1472) {
        const int i = (t - 1472) * 256 + threadIdx.x;
        float4 s = P.s4[i], p = P.p4[i];
        bf16x4 c, q;
        c[0] = f2bf(s.x); c[1] = f2bf(s.y); c[2] = f2bf(s.z); c[3] = f2bf(s.w);
        q[0] = f2bf(s.x + p.x); q[1] = f2bf(s.y + p.y);
        q[2] = f2bf(s.z + p.z); q[3] = f2bf(s.w + p.w);
        ((bf16x4*)P.curb)[i] = c; ((bf16x4*)P.qb)[i] = q;
        return;
    }
    int l = t / 736;
    int u = t % 736;
    const float* src; int K, N; long doff;
    if      (u < 64)  { src = P.Wv;   K = 256;  N = 256;  doff = 0;      }
    else if (u < 128) { src = P.Woff; K = 256;  N = 256;  doff = 65536;  u -= 64;  }
    else if (u < 160) { src = P.Wa;   K = 256;  N = 128;  doff = 131072; u -= 128; }
    else if (u < 224) { src = P.Wo;   K = 256;  N = 256;  doff = 163840; u -= 160; }
    else if (u < 480) { src = P.Wl1;  K = 256;  N = 1024; doff = 229376; u -= 224; }
    else              { src = P.Wl2;  K = 1024; N = 256;  doff = 491520; u -= 480; }
    src += (long)l * K * N;
    short* dst = P.Wt + (long)l * 753664 + doff;

    const int ntx = N / 32;
    const int n0 = (u % ntx) * 32, k0 = (u / ntx) * 32;
    const int tid = threadIdx.x;
    {
        const int n = tid & 31, kq = tid >> 5;
        #pragma unroll
        for (int i = 0; i < 4; ++i) {
            int k = kq * 4 + i;
            T[n * 33 + k] = f2bf(src[(long)(k0 + k) * N + n0 + n]);
        }
    }
    __syncthreads();
    {
        const int k = tid & 31, nq = tid >> 5;
        #pragma unroll
        for (int i = 0; i < 4; ++i) {
            int n = nq * 4 + i;
            dst[(long)(n0 + n) * K + k0 + k] = T[n * 33 + k];
        }
    }
}

// ---------------------------------------------------------------------------
// 128x128 GEMM tile, BK=32, gload_lds 2-buffer counted-vmcnt (R1 structure).
// smem: As @0 (16KB), Bs @16384 (16KB).
// OMODE: 0 f32 row-major, 1 bf16 row-major, 2 bf16 into V planes.
// ---------------------------------------------------------------------------
template <int RELU, int OMODE, int K>
__device__ __forceinline__ void gemm_tile_v2(
    char* smem, const short* __restrict__ A, const short* __restrict__ Wt,
    const float* __restrict__ bias, float* __restrict__ Cf,
    short* __restrict__ Cb, int ldc, int m0, int wrow0, int ccol0)
{
    constexpr int NT = K / 32;
    static_assert(NT >= 4 && (NT & 1) == 0, "NT even >= 4");
    short* As = (short*)smem;
    short* Bs = (short*)(smem + 16384);

    const int t    = threadIdx.x;
    const int wave = t >> 6, lane = t & 63;
    const int wm   = (wave & 1) * 64;
    const int wn   = (wave >> 1) * 64;
    const int lm   = lane & 15;
    const int chkg = lane >> 4;

    const short* aS[2]; const short* bS[2];
    short *aD[2], *bD[2];
    #pragma unroll
    for (int i = 0; i < 2; ++i) {
        const int c   = wave * 2 + i;
        const int row = c * 16 + (lane >> 2);
        const int xc  = (lane & 3) ^ swz(row);
        aS[i] = A  + (long)(m0 + row) * K + xc * 8;
        bS[i] = Wt + (long)(wrow0 + row) * K + xc * 8;
        aD[i] = As + c * 512;
        bD[i] = Bs + c * 512;
    }

    int offA[4], offB[4];
    #pragma unroll
    for (int s = 0; s < 4; ++s) {
        const int r = wm + s * 16 + lm;
        offA[s] = r * 32 + (chkg ^ swz(r)) * 8;
    }
    #pragma unroll
    for (int u = 0; u < 4; ++u) {
        const int r = wn + u * 16 + lm;
        offB[u] = r * 32 + (chkg ^ swz(r)) * 8;
    }

    f32x4 acc[4][4] = {};

#define STG128(BUF, KT) do {                                          \
        const int _ko = (KT) * 32;                                    \
        gload16(aS[0] + _ko, aD[0] + (BUF) * 4096);                   \
        gload16(bS[0] + _ko, bD[0] + (BUF) * 4096);                   \
        gload16(aS[1] + _ko, aD[1] + (BUF) * 4096);                   \
        gload16(bS[1] + _ko, bD[1] + (BUF) * 4096);                   \
    } while (0)

#define GB128(T, BUF, WN, DOSTAGE) do {                               \
        vmwait<WN>();                                                 \
        __builtin_amdgcn_s_barrier();                                 \
        bf16x8 af[4], bv[4];                                          \
        _Pragma("unroll")                                             \
        for (int s = 0; s < 4; ++s)                                   \
            af[s] = *(const bf16x8*)(As + (BUF) * 4096 + offA[s]);    \
        _Pragma("unroll")                                             \
        for (int u = 0; u < 4; ++u)                                   \
            bv[u] = *(const bf16x8*)(Bs + (BUF) * 4096 + offB[u]);    \
        asm volatile("s_waitcnt lgkmcnt(0)" ::: "memory");            \
        __builtin_amdgcn_s_barrier();                                 \
        __builtin_amdgcn_sched_barrier(0);                            \
        if (DOSTAGE) STG128(BUF, (T) + 2);                            \
        _Pragma("unroll")                                             \
        for (int s = 0; s < 4; ++s)                                   \
            _Pragma("unroll")                                         \
            for (int u = 0; u < 4; ++u)                               \
                acc[s][u] = MFMA16(af[s], bv[u], acc[s][u], 0, 0, 0); \
    } while (0)

    STG128(0, 0);
    STG128(1, 1);
    for (int tt = 0; tt < NT - 2; tt += 2) {
        GB128(tt,     0, 4, true);
        GB128(tt + 1, 1, 4, true);
    }
    GB128(NT - 2, 0, 4, false);
    GB128(NT - 1, 1, 0, false);
#undef GB128
#undef STG128

    const int col = lane & 15;
    const int rq  = (lane >> 4) * 4;
    #pragma unroll
    for (int s = 0; s < 4; ++s) {
        #pragma unroll
        for (int u = 0; u < 4; ++u) {
            const int gn = ccol0 + wn + u * 16 + col;
            const float bb = bias[gn];
            #pragma unroll
            for (int r = 0; r < 4; ++r) {
                const int gm = m0 + wm + s * 16 + rq + r;
                float v = acc[s][u][r] + bb;
                if (RELU) v = fmaxf(v, 0.f);
                if (OMODE == 0) {
                    Cf[(long)gm * ldc + gn] = v;
                } else if (OMODE == 1) {
                    Cb[(long)gm * ldc + gn] = f2bf(v);
                } else {
                    const int n   = gm / LEN;
                    const int pix = gm - n * LEN;
                    const int h   = gn >> 5, d = gn & 31;
                    Cb[((long)(n * NH + h) * LEN + pix) * 32 + d] = f2bf(v);
                }
            }
        }
    }
}

// qkv tile dispatcher (layer 0, M128): w in [0,425): n0=(w%5)*128, m0=(w/5)*128.
__device__ __forceinline__ void qkv_tile(
    char* smem, int w, const KParams& P, const short* Wb,
    const float* bv, const float* boff, const float* ba)
{
    const int n0 = (w % 5) * 128, m0 = (w / 5) * 128;
    if (n0 < 256) {
        gemm_tile_v2<0, 2, 256>(smem, P.curb, Wb, bv, (float*)nullptr, P.Vb,
                                256, m0, n0, n0);
    } else if (n0 < 512) {
        gemm_tile_v2<0, 0, 256>(smem, P.qb, Wb, boff, P.OFF, (short*)nullptr,
                                256, m0, n0, n0 - 256);
    } else {
        gemm_tile_v2<0, 0, 256>(smem, P.qb, Wb, ba, P.AW, (short*)nullptr,
                                128, m0, n0, n0 - 512);
    }
}

// ---------------------------------------------------------------------------
// M32 x BN GEMM tile (no LN), derived from the verified ln_tile structure.
// 4 waves: wave covers 16 rows x BN/2 cols. smem: As @0 (4KB), Bs @4096.
// ---------------------------------------------------------------------------
template <int RELU, int OMODE, int K, int BN>
__device__ __forceinline__ void g32_tile(
    char* smem, const short* __restrict__ A, const short* __restrict__ Wt,
    const float* __restrict__ bias, float* __restrict__ Cf,
    short* __restrict__ Cb, int ldc, int m0, int ccol0)
{
    constexpr int NT  = K / 32;
    constexpr int NF  = BN / 32;       // col fragments per wave
    constexpr int CPW = BN / 64;       // B chunks staged per wave
    constexpr int BSTR = BN * 32;      // shorts per B buffer
    constexpr int WA  = CPW + 1;
    constexpr int WB  = CPW;
    static_assert(NT >= 4 && (NT & 1) == 0, "NT even >= 4");
    short* As = (short*)smem;
    short* Bs = (short*)(smem + 4096);

    const int t    = threadIdx.x;
    const int wave = t >> 6, lane = t & 63;
    const int wm   = (wave & 1) * 16;
    const int wn   = (wave >> 1) * (BN / 2);
    const int lm   = lane & 15;
    const int chkg = lane >> 4;
    const int rq   = chkg * 4;
    const bool hasA = (wave & 1) == 0;

    const short* bSp[CPW]; short* bDp[CPW];
    #pragma unroll
    for (int i = 0; i < CPW; ++i) {
        const int c   = wave * CPW + i;
        const int row = c * 16 + (lane >> 2);
        const int xc  = (lane & 3) ^ swz(row);
        bSp[i] = Wt + (long)row * K + xc * 8;
        bDp[i] = Bs + c * 512;
    }
    const short* aSp = nullptr; short* aDp = nullptr;
    if (hasA) {
        const int c   = wave >> 1;
        const int row = c * 16 + (lane >> 2);
        const int xc  = (lane & 3) ^ swz(row);
        aSp = A + (long)(m0 + row) * K + xc * 8;
        aDp = As + c * 512;
    }

    const int offA = (wm + lm) * 32 + (chkg ^ swz(wm + lm)) * 8;
    int offB[NF];
    #pragma unroll
    for (int u = 0; u < NF; ++u) {
        const int r = wn + u * 16 + lm;
        offB[u] = r * 32 + (chkg ^ swz(r)) * 8;
    }

    f32x4 acc[NF] = {};

#define STG32(BUF, KT) do {                                           \
        const int _ko = (KT) * 32;                                    \
        if (hasA) gload16(aSp + _ko, aDp + (BUF) * 1024);             \
        _Pragma("unroll")                                             \
        for (int i = 0; i < CPW; ++i)                                 \
            gload16(bSp[i] + _ko, bDp[i] + (BUF) * BSTR);             \
    } while (0)

#define GB32(T, BUF, AW_, BW_, DOSTAGE) do {                          \
        if (hasA) vmwait<AW_>(); else vmwait<BW_>();                  \
        __builtin_amdgcn_s_barrier();                                 \
        bf16x8 af = *(const bf16x8*)(As + (BUF) * 1024 + offA);       \
        bf16x8 bv[NF];                                                \
        _Pragma("unroll")                                             \
        for (int u = 0; u < NF; ++u)                                  \
            bv[u] = *(const bf16x8*)(Bs + (BUF) * BSTR + offB[u]);    \
        asm volatile("s_waitcnt lgkmcnt(0)" ::: "memory");            \
        __builtin_amdgcn_s_barrier();                                 \
        __builtin_amdgcn_sched_barrier(0);                            \
        if (DOSTAGE) STG32(BUF, (T) + 2);                             \
        _Pragma("unroll")                                             \
        for (int u = 0; u < NF; ++u)                                  \
            acc[u] = MFMA16(af, bv[u], acc[u], 0, 0, 0);              \
    } while (0)

    STG32(0, 0);
    STG32(1, 1);
    for (int tt = 0; tt < NT - 2; tt += 2) {
        GB32(tt,     0, WA, WB, true);
        GB32(tt + 1, 1, WA, WB, true);
    }
    GB32(NT - 2, 0, WA, WB, false);
    GB32(NT - 1, 1, 0, 0, false);
#undef GB32
#undef STG32

    #pragma unroll
    for (int u = 0; u < NF; ++u) {
        const int gn = ccol0 + wn + u * 16 + lm;
        const float bb = bias[gn];
        #pragma unroll
        for (int r = 0; r < 4; ++r) {
            const int gm = m0 + wm + rq + r;
            float v = acc[u][r] + bb;
            if (RELU) v = fmaxf(v, 0.f);
            if (OMODE == 0) {
                Cf[(long)gm * ldc + gn] = v;
            } else if (OMODE == 1) {
                Cb[(long)gm * ldc + gn] = f2bf(v);
            } else {
                const int n   = gm / LEN;
                const int pix = gm - n * LEN;
                const int h   = gn >> 5, d = gn & 31;
                Cb[((long)(n * NH + h) * LEN + pix) * 32 + d] = f2bf(v);
            }
        }
    }
}

// ---------------------------------------------------------------------------
// Fused GEMM + residual + LayerNorm tile (M=32, N=256), R1 structure.
// smem: As @0 (4KB), Bs @4096 (32KB), red @36864 (512B).
// ---------------------------------------------------------------------------
template <int K>
__device__ __forceinline__ void ln_tile_v2(
    char* smem, const short* __restrict__ A, const short* __restrict__ Wt,
    const float* __restrict__ bias, const short* __restrict__ residb,
    const float* __restrict__ g, const float* __restrict__ be,
    short* __restrict__ outb, short* __restrict__ outq,
    float* __restrict__ outf, const float* __restrict__ pos, int m0)
{
    constexpr int NT = K / 32;
    short* As = (short*)smem;
    short* Bs = (short*)(smem + 4096);
    float (*red)[32][2] = (float (*)[32][2])(smem + 36864);

    const int t    = threadIdx.x;
    const int wave = t >> 6, lane = t & 63;
    const int wm   = (wave & 1) * 16;
    const int wn   = (wave >> 1) * 128;
    const int lm   = lane & 15;
    const int chkg = lane >> 4;
    const int rq   = chkg * 4;
    const bool hasA = (wave & 1) == 0;

    short rr[8][4];
    #pragma unroll
    for (int u = 0; u < 8; ++u)
        #pragma unroll
        for (int r = 0; r < 4; ++r)
            rr[u][r] = residb[(long)(m0 + wm + rq + r) * DM + wn + u * 16 + lm];
    asm volatile("" ::: "memory");

    const short* bSp[4]; short* bDp[4];
    #pragma unroll
    for (int i = 0; i < 4; ++i) {
        const int c   = wave * 4 + i;
        const int row = c * 16 + (lane >> 2);
        const int xc  = (lane & 3) ^ swz(row);
        bSp[i] = Wt + (long)row * K + xc * 8;
        bDp[i] = Bs + c * 512;
    }
    const short* aSp = nullptr; short* aDp = nullptr;
    if (hasA) {
        const int c   = wave >> 1;
        const int row = c * 16 + (lane >> 2);
        const int xc  = (lane & 3) ^ swz(row);
        aSp = A + (long)(m0 + row) * K + xc * 8;
        aDp = As + c * 512;
    }

    const int offA = (wm + lm) * 32 + (chkg ^ swz(wm + lm)) * 8;
    int offB[8];
    #pragma unroll
    for (int u = 0; u < 8; ++u) {
        const int r = wn + u * 16 + lm;
        offB[u] = r * 32 + (chkg ^ swz(r)) * 8;
    }

    f32x4 acc[8] = {};

#define STGL(BUF, KT) do {                                            \
        const int _ko = (KT) * 32;                                    \
        if (hasA) gload16(aSp + _ko, aDp + (BUF) * 1024);             \
        gload16(bSp[0] + _ko, bDp[0] + (BUF) * 8192);                 \
        gload16(bSp[1] + _ko, bDp[1] + (BUF) * 8192);                 \
        gload16(bSp[2] + _ko, bDp[2] + (BUF) * 8192);                 \
        gload16(bSp[3] + _ko, bDp[3] + (BUF) * 8192);                 \
    } while (0)

#define GBLN(T, BUF, WA, WB, DOSTAGE) do {                            \
        if (hasA) vmwait<WA>(); else vmwait<WB>();                    \
        __builtin_amdgcn_s_barrier();                                 \
        bf16x8 af = *(const bf16x8*)(As + (BUF) * 1024 + offA);       \
        bf16x8 bv[8];                                                 \
        _Pragma("unroll")                                             \
        for (int u = 0; u < 8; ++u)                                   \
            bv[u] = *(const bf16x8*)(Bs + (BUF) * 8192 + offB[u]);    \
        asm volatile("s_waitcnt lgkmcnt(0)" ::: "memory");            \
        __builtin_amdgcn_s_barrier();                                 \
        __builtin_amdgcn_sched_barrier(0);                            \
        if (DOSTAGE) STGL(BUF, (T) + 2);                              \
        _Pragma("unroll")                                             \
        for (int u = 0; u < 8; ++u)                                   \
            acc[u] = MFMA16(af, bv[u], acc[u], 0, 0, 0);              \
    } while (0)

    STGL(0, 0);
    STGL(1, 1);
    for (int tt = 0; tt < NT - 2; tt += 2) {
        GBLN(tt,     0, 5, 4, true);
        GBLN(tt + 1, 1, 5, 4, true);
    }
    GBLN(NT - 2, 0, 5, 4, false);
    GBLN(NT - 1, 1, 0, 0, false);
#undef GBLN
#undef STGL

    #pragma unroll
    for (int u = 0; u < 8; ++u) {
        const int gn = wn + u * 16 + lm;
        const float bb = bias[gn];
        #pragma unroll
        for (int r = 0; r < 4; ++r)
            acc[u][r] += bb + bf2f(rr[u][r]);
    }

    float rs[4], r2[4];
    #pragma unroll
    for (int r = 0; r < 4; ++r) {
        float s = 0.f, s2 = 0.f;
        #pragma unroll
        for (int u = 0; u < 8; ++u) { const float v = acc[u][r]; s += v; s2 += v * v; }
        rs[r] = s; r2[r] = s2;
    }
    #pragma unroll
    for (int o = 1; o < 16; o <<= 1)
        #pragma unroll
        for (int r = 0; r < 4; ++r) {
            rs[r] += __shfl_xor(rs[r], o, 64);
            r2[r] += __shfl_xor(r2[r], o, 64);
        }
    if (lm == 0) {
        #pragma unroll
        for (int r = 0; r < 4; ++r) {
            red[wave >> 1][wm + rq + r][0] = rs[r];
            red[wave >> 1][wm + rq + r][1] = r2[r];
        }
    }
    __syncthreads();
    #pragma unroll
    for (int r = 0; r < 4; ++r) {
        const int row = wm + rq + r;
        const float ts = red[0][row][0] + red[1][row][0];
        const float t2 = red[0][row][1] + red[1][row][1];
        const float mean = ts * (1.f / DM);
        const float var  = t2 * (1.f / DM) - mean * mean;
        rs[r] = mean;
        r2[r] = rsqrtf(var + 1e-5f);
    }
    #pragma unroll
    for (int u = 0; u < 8; ++u) {
        const int gn = wn + u * 16 + lm;
        const float gg = g[gn], bbe = be[gn];
        #pragma unroll
        for (int r = 0; r < 4; ++r) {
            const long gm = m0 + wm + rq + r;
            const float o = (acc[u][r] - rs[r]) * r2[r] * gg + bbe;
            if (outb) outb[gm * DM + gn] = f2bf(o);
            if (outq) outq[gm * DM + gn] = f2bf(o + pos[gm * DM + gn]);
            if (outf) outf[gm * DM + gn] = o;
        }
    }
}

// ---------------------------------------------------------------------------
// Deformable attention sampling unit (bx in [0,2720)): 4 queries, wave each.
// ---------------------------------------------------------------------------
__device__ __forceinline__ void deform_unit(
    int bx, const short* __restrict__ Vb, const float* __restrict__ OFF,
    const float* __restrict__ AW, const float* __restrict__ vr,
    bf16x4* __restrict__ ATTb)
{
    const int starts[5] = {0, 4096, 5120, 5376, 5440};
    const int dims[4]   = {64, 32, 16, 8};

    const int wave = threadIdx.x >> 6;
    const int lane = threadIdx.x & 63;
    const int h    = lane >> 3;
    const int d4   = lane & 7;

    const int gq = bx * 4 + wave;
    const int n  = gq / LEN;
    const int q  = gq % LEN;

    int lq = 3;
    if (q < 4096) lq = 0; else if (q < 5120) lq = 1; else if (q < 5376) lq = 2;
    const int r  = q - starts[lq];
    const int Wq = dims[lq];
    const int gy = r / Wq, gx = r % Wq;
    const float vrxq = vr[(n * NLV + lq) * 2 + 0];
    const float vryq = vr[(n * NLV + lq) * 2 + 1];
    const float rx = (gx + 0.5f) / (vrxq * Wq);
    const float ry = (gy + 0.5f) / (vryq * Wq);

    const long row = (long)n * LEN + q;

    const float* awp = AW + row * 128 + h * 16;
    float a[16];
    float mx = -1e30f;
    #pragma unroll
    for (int i = 0; i < 16; ++i) { a[i] = awp[i]; mx = fmaxf(mx, a[i]); }
    float s = 0.f;
    #pragma unroll
    for (int i = 0; i < 16; ++i) { a[i] = __expf(a[i] - mx); s += a[i]; }
    const float inv = 1.f / s;

    const float* offp = OFF + row * 256 + h * 32;

    float4 acc = {0.f, 0.f, 0.f, 0.f};
    #pragma unroll
    for (int lvl = 0; lvl < NLV; ++lvl) {
        const int Hl = dims[lvl];
        const int Wl = Hl;
        const float fW = (float)Wl;
        const int sb = starts[lvl];
        const float lx = rx * vr[(n * NLV + lvl) * 2 + 0];
        const float ly = ry * vr[(n * NLV + lvl) * 2 + 1];
        const short* vb = Vb + ((long)(n * NH + h) * LEN + sb) * 32 + d4 * 4;
        #pragma unroll
        for (int p = 0; p < NPT; ++p) {
            const float ox = offp[lvl * 8 + p * 2 + 0];
            const float oy = offp[lvl * 8 + p * 2 + 1];
            const float x = fmaf(lx, fW, ox) - 0.5f;
            const float y = fmaf(ly, fW, oy) - 0.5f;
            const float x0f = floorf(x), y0f = floorf(y);
            const int ix0 = (int)x0f, iy0 = (int)y0f;
            const float wx1 = x - x0f, wy1 = y - y0f;
            const float wx0 = 1.f - wx1, wy0 = 1.f - wy1;

            const bool vx0 = (ix0 >= 0)     && (ix0 < Wl);
            const bool vx1 = (ix0 + 1 >= 0) && (ix0 + 1 < Wl);
            const bool vy0 = (iy0 >= 0)     && (iy0 < Hl);
            const bool vy1 = (iy0 + 1 >= 0) && (iy0 + 1 < Hl);
            const int cx0 = min(max(ix0, 0), Wl - 1);
            const int cx1 = min(max(ix0 + 1, 0), Wl - 1);
            const int cy0 = min(max(iy0, 0), Hl - 1);
            const int cy1 = min(max(iy0 + 1, 0), Hl - 1);

            const float w00 = (vx0 && vy0) ? wx0 * wy0 : 0.f;
            const float w10 = (vx1 && vy0) ? wx1 * wy0 : 0.f;
            const float w01 = (vx0 && vy1) ? wx0 * wy1 : 0.f;
            const float w11 = (vx1 && vy1) ? wx1 * wy1 : 0.f;

            const bf16x4 g00 = *(const bf16x4*)(vb + (long)(cy0 * Wl + cx0) * 32);
            const bf16x4 g10 = *(const bf16x4*)(vb + (long)(cy0 * Wl + cx1) * 32);
            const bf16x4 g01 = *(const bf16x4*)(vb + (long)(cy1 * Wl + cx0) * 32);
            const bf16x4 g11 = *(const bf16x4*)(vb + (long)(cy1 * Wl + cx1) * 32);

            const float awv = a[lvl * 4 + p] * inv;
            #pragma unroll
            for (int e = 0; e < 4; ++e) {
                float sv = w00 * bf2f(g00[e]) + w10 * bf2f(g10[e])
                         + w01 * bf2f(g01[e]) + w11 * bf2f(g11[e]);
                (&acc.x)[e] += awv * sv;
            }
        }
    }
    bf16x4 ob;
    ob[0] = f2bf(acc.x); ob[1] = f2bf(acc.y);
    ob[2] = f2bf(acc.z); ob[3] = f2bf(acc.w);
    ATTb[row * 64 + h * 8 + d4] = ob;
}

// ---------------------------------------------------------------------------
// Kernels. Pipeline: prep -> qkv(L0, M128) -> fused(L0) -> fused(L1).
// fused: per-block 32 rows, row-local chain deform -> ln1 -> ffn1 -> ln2
// [-> qkv(L1)]. Only cross-block dep (Vb gather) sits at dispatch boundaries;
// Vb is double-buffered (Vb layer0, Vb1 layer1) to kill the WAR race.
// ---------------------------------------------------------------------------
__global__ __launch_bounds__(256) void prep_k(KParams P)
{
    __shared__ __align__(16) short T[32 * 33];
    prep_unit(blockIdx.x, P, T);
}

__global__ __launch_bounds__(256) void qkv_k(KParams P)
{
    __shared__ __align__(16) char smem[32768];
    qkv_tile(smem, blockIdx.x, P, P.Wt, P.bv, P.boff, P.ba);
}

__global__ __launch_bounds__(256) void fused_k(KParams P, int l)
{
    __shared__ __align__(16) char smem[37888];
    const int m0 = blockIdx.x * 32;
    const long lo = (long)l;
    const short* Wb   = P.Wt + lo * 753664;
    const float* bo   = P.bo  + lo * DM;
    const float* g1   = P.g1  + lo * DM;
    const float* be1  = P.be1 + lo * DM;
    const float* bl1  = P.bl1 + lo * DFFN;
    const float* bl2  = P.bl2 + lo * DM;
    const float* g2   = P.g2  + lo * DM;
    const float* be2  = P.be2 + lo * DM;
    const short* VbL  = l ? P.Vb1 : P.Vb;

    // ---- deform: rows m0..m0+31 (8 groups of 4 queries) ----
    #pragma unroll 1
    for (int u = 0; u < 8; ++u)
        deform_unit(m0 / 4 + u, VbL, P.OFF, P.AW, P.vr, (bf16x4*)P.ATTb);
    __syncthreads();   // drain ATTb stores

    // ---- ln1: XAb = LN(curb + ATT@Wo + bo) ----
    ln_tile_v2<256>(smem, P.ATTb, Wb + 163840, bo, P.curb, g1, be1,
                    P.XAb, (short*)nullptr, (float*)nullptr,
                    (const float*)nullptr, m0);
    __syncthreads();   // drain XAb stores

    // ---- ffn1: FFNb = relu(XAb @ Wl1 + bl1), 4 x (32x256) col tiles ----
    #pragma unroll 1
    for (int i = 0; i < 4; ++i)
        g32_tile<1, 1, 256, 256>(smem, P.XAb, Wb + 229376 + (long)i * 256 * 256,
                                 bl1, (float*)nullptr, P.FFNb, DFFN, m0, i * 256);
    __syncthreads();   // drain FFNb stores

    // ---- ln2 (+ layer-1 qkv for own rows when l==0) ----
    if (l == 0) {
        ln_tile_v2<1024>(smem, P.FFNb, Wb + 491520, bl2, P.XAb, g2, be2,
                         P.curb, P.qb, (float*)nullptr, P.pos, m0);
        __syncthreads();   // drain curb/qb stores
        const short* Wb1 = P.Wt + 753664;
        g32_tile<0, 2, 256, 256>(smem, P.curb, Wb1, P.bv + DM,
                                 (float*)nullptr, P.Vb1, 256, m0, 0);
        g32_tile<0, 0, 256, 256>(smem, P.qb, Wb1 + 65536, P.boff + 256,
                                 P.OFF, (short*)nullptr, 256, m0, 0);
        g32_tile<0, 0, 256, 128>(smem, P.qb, Wb1 + 131072, P.ba + 128,
                                 P.AW, (short*)nullptr, 128, m0, 0);
    } else {
        ln_tile_v2<1024>(smem, P.FFNb, Wb + 491520, bl2, P.XAb, g2, be2,
                         (short*)nullptr, (short*)nullptr, P.out,
                         (const float*)nullptr, m0);
    }
}

// ---------------------------------------------------------------------------
extern "C" void kernel_launch(void* const* d_in, const int* in_sizes, int n_in,
                              void* d_out, int out_size, void* d_ws, size_t ws_size,
                              hipStream_t stream)
{
    const long SZ = (long)MROWS * DM;        // 2,785,280 elements
    float* ws = (float*)d_ws;

    KParams P;
    P.s4   = (const float4*)d_in[0];
    P.p4   = (const float4*)d_in[1];
    P.pos  = (const float*)d_in[1];
    P.vr   = (const float*)d_in[2];
    P.Wv   = (const float*)d_in[3];
    P.bv   = (const float*)d_in[4];
    P.Woff = (const float*)d_in[5];
    P.boff = (const float*)d_in[6];
    P.Wa   = (const float*)d_in[7];
    P.ba   = (const float*)d_in[8];
    P.Wo   = (const float*)d_in[9];
    P.bo   = (const float*)d_in[10];
    P.g1   = (const float*)d_in[11];
    P.be1  = (const float*)d_in[12];
    P.Wl1  = (const float*)d_in[13];
    P.bl1  = (const float*)d_in[14];
    P.Wl2  = (const float*)d_in[15];
    P.bl2  = (const float*)d_in[16];
    P.g2   = (const float*)d_in[17];
    P.be2  = (const float*)d_in[18];

    P.OFF  = ws;
    P.AW   = P.OFF + SZ;
    P.Vb   = (short*)(P.AW + (long)MROWS * 128);
    P.curb = P.Vb   + SZ;
    P.qb   = P.curb + SZ;
    P.ATTb = P.qb   + SZ;
    P.XAb  = P.ATTb + SZ;
    P.FFNb = P.XAb  + SZ;
    P.Wt   = P.FFNb + (long)MROWS * DFFN;
    P.Vb1  = P.Wt   + 2L * 753664;
    P.out  = (float*)d_out;

    const dim3 blk(256);
    hipLaunchKernelGGL(prep_k,  dim3(4192), blk, 0, stream, P);
    hipLaunchKernelGGL(qkv_k,   dim3(425),  blk, 0, stream, P);
    hipLaunchKernelGGL(fused_k, dim3(340),  blk, 0, stream, P, 0);
    hipLaunchKernelGGL(fused_k, dim3(340),  blk, 0, stream, P, 1);
}

// Round 5
// 293.822 us; speedup vs baseline: 4.7712x; 1.4034x over previous
//
#include <hip/hip_runtime.h>
#include <math.h>

#define LEN   5440
#define NB    2
#define MROWS (NB * LEN)   // 10880
#define DM    256
#define NH    8
#define HD    32
#define NLV   4
#define NPT   4
#define DFFN  1024

typedef __attribute__((ext_vector_type(8))) short bf16x8;
typedef __attribute__((ext_vector_type(4))) short bf16x4;
typedef __attribute__((ext_vector_type(4))) float f32x4;

#define MFMA16 __builtin_amdgcn_mfma_f32_16x16x32_bf16

__device__ __forceinline__ short f2bf(float f) {
    union { float f; unsigned u; } cv; cv.f = f;
    unsigned r = cv.u + 0x7fffu + ((cv.u >> 16) & 1u);   // RNE
    return (short)(r >> 16);
}
__device__ __forceinline__ float bf2f(short s) {
    union { unsigned u; float f; } cv;
    cv.u = ((unsigned)(unsigned short)s) << 16;
    return cv.f;
}

__device__ __forceinline__ void gload16(const short* g, short* l) {
    __builtin_amdgcn_global_load_lds(
        (__attribute__((address_space(1))) void*)g,
        (__attribute__((address_space(3))) void*)l, 16, 0, 0);
}

template <int N> __device__ __forceinline__ void vmwait();
template <> __device__ __forceinline__ void vmwait<0>() { asm volatile("s_waitcnt vmcnt(0)" ::: "memory"); }
template <> __device__ __forceinline__ void vmwait<4>() { asm volatile("s_waitcnt vmcnt(4)" ::: "memory"); }
template <> __device__ __forceinline__ void vmwait<5>() { asm volatile("s_waitcnt vmcnt(5)" ::: "memory"); }

// chunk swizzle within a 64B row-slice (4 x 16B chunks): phys = logical ^ swz(row).
__device__ __forceinline__ int swz(int row) { return (row >> 1) & 3; }

// ---------------------------------------------------------------------------
// Merged one-shot prep: blocks [0,1472) transpose+convert the 12 weight
// matrices fp32 [K][N] -> bf16 [N][K]; blocks [1472,4192) convert
// src -> bf16(src), bf16(src+pos).
// ---------------------------------------------------------------------------
__global__ __launch_bounds__(256) void prep_all(
    const float* __restrict__ Wv,  const float* __restrict__ Woff,
    const float* __restrict__ Wa,  const float* __restrict__ Wo,
    const float* __restrict__ Wl1, const float* __restrict__ Wl2,
    short* __restrict__ out,
    const float4* __restrict__ s4, const float4* __restrict__ p4,
    bf16x4* __restrict__ curb, bf16x4* __restrict__ qb)
{
    __shared__ short T[32][33];
    if (blockIdx.x >= 1472) {
        const int i = (blockIdx.x - 1472) * 256 + threadIdx.x;
        float4 s = s4[i], p = p4[i];
        bf16x4 c, q;
        c[0] = f2bf(s.x); c[1] = f2bf(s.y); c[2] = f2bf(s.z); c[3] = f2bf(s.w);
        q[0] = f2bf(s.x + p.x); q[1] = f2bf(s.y + p.y);
        q[2] = f2bf(s.z + p.z); q[3] = f2bf(s.w + p.w);
        curb[i] = c; qb[i] = q;
        return;
    }
    int bx = blockIdx.x;
    int l  = bx / 736;
    int t  = bx % 736;
    const float* src; int K, N; long doff;
    if      (t < 64)  { src = Wv;   K = 256;  N = 256;  doff = 0;      }
    else if (t < 128) { src = Woff; K = 256;  N = 256;  doff = 65536;  t -= 64;  }
    else if (t < 160) { src = Wa;   K = 256;  N = 128;  doff = 131072; t -= 128; }
    else if (t < 224) { src = Wo;   K = 256;  N = 256;  doff = 163840; t -= 160; }
    else if (t < 480) { src = Wl1;  K = 256;  N = 1024; doff = 229376; t -= 224; }
    else              { src = Wl2;  K = 1024; N = 256;  doff = 491520; t -= 480; }
    src += (long)l * K * N;
    short* dst = out + (long)l * 753664 + doff;

    const int ntx = N / 32;
    const int n0 = (t % ntx) * 32, k0 = (t / ntx) * 32;

    const int tid = threadIdx.x;
    {
        const int n = tid & 31, kq = tid >> 5;
        #pragma unroll
        for (int i = 0; i < 4; ++i) {
            int k = kq * 4 + i;
            T[n][k] = f2bf(src[(long)(k0 + k) * N + n0 + n]);
        }
    }
    __syncthreads();
    {
        const int k = tid & 31, nq = tid >> 5;
        #pragma unroll
        for (int i = 0; i < 4; ++i) {
            int n = nq * 4 + i;
            dst[(long)(n0 + n) * K + k0 + k] = T[n][k];
        }
    }
}

// ---------------------------------------------------------------------------
// MFMA bf16 GEMM core v2 (R1, 292us-verified): 128x128 tile, BK=32,
// global_load_lds 2-buffer counted-vmcnt staging.
// OMODE: 0 f32 row-major, 1 bf16 row-major, 2 bf16 into V planes.
// ---------------------------------------------------------------------------
template <int RELU, int OMODE, int K>
__device__ __forceinline__ void gemm_core128_v2(
    short* As, short* Bs,
    const short* __restrict__ A, const short* __restrict__ Wt,
    const float* __restrict__ bias, float* __restrict__ Cf,
    short* __restrict__ Cb, int ldc, int m0, int wrow0, int ccol0)
{
    constexpr int NT = K / 32;
    static_assert(NT >= 4 && (NT & 1) == 0, "NT even >= 4");
    const int t    = threadIdx.x;
    const int wave = t >> 6, lane = t & 63;
    const int wm   = (wave & 1) * 64;
    const int wn   = (wave >> 1) * 64;
    const int lm   = lane & 15;
    const int chkg = lane >> 4;

    const short* aS[2]; const short* bS[2];
    short *aD[2], *bD[2];
    #pragma unroll
    for (int i = 0; i < 2; ++i) {
        const int c   = wave * 2 + i;
        const int row = c * 16 + (lane >> 2);
        const int xc  = (lane & 3) ^ swz(row);
        aS[i] = A  + (long)(m0 + row) * K + xc * 8;
        bS[i] = Wt + (long)(wrow0 + row) * K + xc * 8;
        aD[i] = As + c * 512;
        bD[i] = Bs + c * 512;
    }

    int offA[4], offB[4];
    #pragma unroll
    for (int s = 0; s < 4; ++s) {
        const int r = wm + s * 16 + lm;
        offA[s] = r * 32 + (chkg ^ swz(r)) * 8;
    }
    #pragma unroll
    for (int u = 0; u < 4; ++u) {
        const int r = wn + u * 16 + lm;
        offB[u] = r * 32 + (chkg ^ swz(r)) * 8;
    }

    f32x4 acc[4][4] = {};

#define STG128(BUF, KT) do {                                          \
        const int _ko = (KT) * 32;                                    \
        gload16(aS[0] + _ko, aD[0] + (BUF) * 4096);                   \
        gload16(bS[0] + _ko, bD[0] + (BUF) * 4096);                   \
        gload16(aS[1] + _ko, aD[1] + (BUF) * 4096);                   \
        gload16(bS[1] + _ko, bD[1] + (BUF) * 4096);                   \
    } while (0)

#define GB128(T, BUF, WN, DOSTAGE) do {                               \
        vmwait<WN>();                                                 \
        __builtin_amdgcn_s_barrier();                                 \
        bf16x8 af[4], bv[4];                                          \
        _Pragma("unroll")                                             \
        for (int s = 0; s < 4; ++s)                                   \
            af[s] = *(const bf16x8*)(As + (BUF) * 4096 + offA[s]);    \
        _Pragma("unroll")                                             \
        for (int u = 0; u < 4; ++u)                                   \
            bv[u] = *(const bf16x8*)(Bs + (BUF) * 4096 + offB[u]);    \
        asm volatile("s_waitcnt lgkmcnt(0)" ::: "memory");            \
        __builtin_amdgcn_s_barrier();                                 \
        __builtin_amdgcn_sched_barrier(0);                            \
        if (DOSTAGE) STG128(BUF, (T) + 2);                            \
        _Pragma("unroll")                                             \
        for (int s = 0; s < 4; ++s)                                   \
            _Pragma("unroll")                                         \
            for (int u = 0; u < 4; ++u)                               \
                acc[s][u] = MFMA16(af[s], bv[u], acc[s][u], 0, 0, 0); \
    } while (0)

    STG128(0, 0);
    STG128(1, 1);
    for (int tt = 0; tt < NT - 2; tt += 2) {
        GB128(tt,     0, 4, true);
        GB128(tt + 1, 1, 4, true);
    }
    GB128(NT - 2, 0, 4, false);
    GB128(NT - 1, 1, 0, false);
#undef GB128
#undef STG128

    const int col = lane & 15;
    const int rq  = (lane >> 4) * 4;
    #pragma unroll
    for (int s = 0; s < 4; ++s) {
        #pragma unroll
        for (int u = 0; u < 4; ++u) {
            const int gn = ccol0 + wn + u * 16 + col;
            const float bb = bias[gn];
            #pragma unroll
            for (int r = 0; r < 4; ++r) {
                const int gm = m0 + wm + s * 16 + rq + r;
                float v = acc[s][u][r] + bb;
                if (RELU) v = fmaxf(v, 0.f);
                if (OMODE == 0) {
                    Cf[(long)gm * ldc + gn] = v;
                } else if (OMODE == 1) {
                    Cb[(long)gm * ldc + gn] = f2bf(v);
                } else {
                    const int n   = gm / LEN;
                    const int pix = gm - n * LEN;
                    const int h   = gn >> 5, d = gn & 31;
                    Cb[((long)(n * NH + h) * LEN + pix) * 32 + d] = f2bf(v);
                }
            }
        }
    }
}

template <int RELU, int OMODE, int K>
__global__ __launch_bounds__(256) void gemm128v2(
    const short* __restrict__ A, const short* __restrict__ Wt,
    const float* __restrict__ bias, float* Cf, short* Cb, int ldc)
{
    __shared__ __align__(16) short As[2 * 128 * 32];
    __shared__ __align__(16) short Bs[2 * 128 * 32];
    gemm_core128_v2<RELU, OMODE, K>(As, Bs, A, Wt, bias, Cf, Cb, ldc,
                                    blockIdx.y * 128, blockIdx.x * 128,
                                    blockIdx.x * 128);
}

// Fused query-side GEMM: [Vb | OFF | AW] over N=640 (Wv|Woff|Wa rows contiguous).
__global__ __launch_bounds__(256) void gemm_qkv128(
    const short* __restrict__ curb, const short* __restrict__ qb,
    const short* __restrict__ Wt, const float* __restrict__ bv,
    const float* __restrict__ boff, const float* __restrict__ ba,
    short* __restrict__ Vb, float* __restrict__ OFF, float* __restrict__ AW)
{
    __shared__ __align__(16) short As[2 * 128 * 32];
    __shared__ __align__(16) short Bs[2 * 128 * 32];
    const int n0 = blockIdx.x * 128;   // 0,128,256,384,512
    if (n0 < 256) {
        gemm_core128_v2<0, 2, 256>(As, Bs, curb, Wt, bv, (float*)nullptr, Vb,
                                   256, blockIdx.y * 128, n0, n0);
    } else if (n0 < 512) {
        gemm_core128_v2<0, 0, 256>(As, Bs, qb, Wt, boff, OFF, (short*)nullptr,
                                   256, blockIdx.y * 128, n0, n0 - 256);
    } else {
        gemm_core128_v2<0, 0, 256>(As, Bs, qb, Wt, ba, AW, (short*)nullptr,
                                   128, blockIdx.y * 128, n0, n0 - 512);
    }
}

// ---------------------------------------------------------------------------
// Fused GEMM + residual(bf16) + LayerNorm, M32 tile, N=256 (R1 structure).
// Used for ln1 (K=256) only; ln2 is split-K below.
// ---------------------------------------------------------------------------
template <int K>
__global__ __launch_bounds__(256) void gemm_ln(
    const short* __restrict__ A, const short* __restrict__ Wt,
    const float* __restrict__ bias, const short* __restrict__ residb,
    const float* __restrict__ g, const float* __restrict__ be,
    short* __restrict__ outb, short* __restrict__ outq,
    float* __restrict__ outf, const float* __restrict__ pos)
{
    constexpr int NT = K / 32;
    __shared__ __align__(16) short As[2 * 32 * 32];
    __shared__ __align__(16) short Bs[2 * 256 * 32];
    __shared__ float red[2][32][2];

    const int t    = threadIdx.x;
    const int wave = t >> 6, lane = t & 63;
    const int wm   = (wave & 1) * 16;
    const int wn   = (wave >> 1) * 128;
    const int lm   = lane & 15;
    const int chkg = lane >> 4;
    const int rq   = chkg * 4;
    const int m0   = blockIdx.x * 32;
    const bool hasA = (wave & 1) == 0;

    short rr[8][4];
    #pragma unroll
    for (int u = 0; u < 8; ++u)
        #pragma unroll
        for (int r = 0; r < 4; ++r)
            rr[u][r] = residb[(long)(m0 + wm + rq + r) * DM + wn + u * 16 + lm];
    asm volatile("" ::: "memory");

    const short* bSp[4]; short* bDp[4];
    #pragma unroll
    for (int i = 0; i < 4; ++i) {
        const int c   = wave * 4 + i;
        const int row = c * 16 + (lane >> 2);
        const int xc  = (lane & 3) ^ swz(row);
        bSp[i] = Wt + (long)row * K + xc * 8;
        bDp[i] = Bs + c * 512;
    }
    const short* aSp = nullptr; short* aDp = nullptr;
    if (hasA) {
        const int c   = wave >> 1;
        const int row = c * 16 + (lane >> 2);
        const int xc  = (lane & 3) ^ swz(row);
        aSp = A + (long)(m0 + row) * K + xc * 8;
        aDp = As + c * 512;
    }

    const int offA = (wm + lm) * 32 + (chkg ^ swz(wm + lm)) * 8;
    int offB[8];
    #pragma unroll
    for (int u = 0; u < 8; ++u) {
        const int r = wn + u * 16 + lm;
        offB[u] = r * 32 + (chkg ^ swz(r)) * 8;
    }

    f32x4 acc[8] = {};

#define STGL(BUF, KT) do {                                            \
        const int _ko = (KT) * 32;                                    \
        if (hasA) gload16(aSp + _ko, aDp + (BUF) * 1024);             \
        gload16(bSp[0] + _ko, bDp[0] + (BUF) * 8192);                 \
        gload16(bSp[1] + _ko, bDp[1] + (BUF) * 8192);                 \
        gload16(bSp[2] + _ko, bDp[2] + (BUF) * 8192);                 \
        gload16(bSp[3] + _ko, bDp[3] + (BUF) * 8192);                 \
    } while (0)

#define GBLN(T, BUF, WA, WB, DOSTAGE) do {                            \
        if (hasA) vmwait<WA>(); else vmwait<WB>();                    \
        __builtin_amdgcn_s_barrier();                                 \
        bf16x8 af = *(const bf16x8*)(As + (BUF) * 1024 + offA);       \
        bf16x8 bv[8];                                                 \
        _Pragma("unroll")                                             \
        for (int u = 0; u < 8; ++u)                                   \
            bv[u] = *(const bf16x8*)(Bs + (BUF) * 8192 + offB[u]);    \
        asm volatile("s_waitcnt lgkmcnt(0)" ::: "memory");            \
        __builtin_amdgcn_s_barrier();                                 \
        __builtin_amdgcn_sched_barrier(0);                            \
        if (DOSTAGE) STGL(BUF, (T) + 2);                              \
        _Pragma("unroll")                                             \
        for (int u = 0; u < 8; ++u)                                   \
            acc[u] = MFMA16(af, bv[u], acc[u], 0, 0, 0);              \
    } while (0)

    STGL(0, 0);
    STGL(1, 1);
    for (int tt = 0; tt < NT - 2; tt += 2) {
        GBLN(tt,     0, 5, 4, true);
        GBLN(tt + 1, 1, 5, 4, true);
    }
    GBLN(NT - 2, 0, 5, 4, false);
    GBLN(NT - 1, 1, 0, 0, false);
#undef GBLN
#undef STGL

    #pragma unroll
    for (int u = 0; u < 8; ++u) {
        const int gn = wn + u * 16 + lm;
        const float bb = bias[gn];
        #pragma unroll
        for (int r = 0; r < 4; ++r)
            acc[u][r] += bb + bf2f(rr[u][r]);
    }

    float rs[4], r2[4];
    #pragma unroll
    for (int r = 0; r < 4; ++r) {
        float s = 0.f, s2 = 0.f;
        #pragma unroll
        for (int u = 0; u < 8; ++u) { const float v = acc[u][r]; s += v; s2 += v * v; }
        rs[r] = s; r2[r] = s2;
    }
    #pragma unroll
    for (int o = 1; o < 16; o <<= 1)
        #pragma unroll
        for (int r = 0; r < 4; ++r) {
            rs[r] += __shfl_xor(rs[r], o, 64);
            r2[r] += __shfl_xor(r2[r], o, 64);
        }
    if (lm == 0) {
        #pragma unroll
        for (int r = 0; r < 4; ++r) {
            red[wave >> 1][wm + rq + r][0] = rs[r];
            red[wave >> 1][wm + rq + r][1] = r2[r];
        }
    }
    __syncthreads();
    #pragma unroll
    for (int r = 0; r < 4; ++r) {
        const int row = wm + rq + r;
        const float ts = red[0][row][0] + red[1][row][0];
        const float t2 = red[0][row][1] + red[1][row][1];
        const float mean = ts * (1.f / DM);
        const float var  = t2 * (1.f / DM) - mean * mean;
        rs[r] = mean;
        r2[r] = rsqrtf(var + 1e-5f);
    }
    #pragma unroll
    for (int u = 0; u < 8; ++u) {
        const int gn = wn + u * 16 + lm;
        const float gg = g[gn], bbe = be[gn];
        #pragma unroll
        for (int r = 0; r < 4; ++r) {
            const long gm = m0 + wm + rq + r;
            const float o = (acc[u][r] - rs[r]) * r2[r] * gg + bbe;
            if (outb) outb[gm * DM + gn] = f2bf(o);
            if (outq) outq[gm * DM + gn] = f2bf(o + pos[gm * DM + gn]);
            if (outf) outf[gm * DM + gn] = o;
        }
    }
}

// ---------------------------------------------------------------------------
// Split-K ln2, part 1: PART[kk] = FFNb[:, kk*512:+512] @ Wl2t[:, kk*512:+512]
// M32xN256 tile per block, grid (2, 340). Same verified staging structure as
// gemm_ln but K-slice (KLEN) of a larger row stride (KSTR), f32 out, no bias.
// ---------------------------------------------------------------------------
template <int KLEN, int KSTR>
__global__ __launch_bounds__(256) void ln2_part_k(
    const short* __restrict__ A0, const short* __restrict__ Wt0,
    float* __restrict__ PART)
{
    constexpr int NT = KLEN / 32;
    static_assert(NT >= 4 && (NT & 1) == 0, "NT even >= 4");
    __shared__ __align__(16) short As[2 * 32 * 32];
    __shared__ __align__(16) short Bs[2 * 256 * 32];

    const int kk = blockIdx.x;                 // K-half 0/1
    const int m0 = blockIdx.y * 32;
    const short* A  = A0  + kk * KLEN;
    const short* Wt = Wt0 + kk * KLEN;
    float* Pout = PART + (long)kk * MROWS * DM;

    const int t    = threadIdx.x;
    const int wave = t >> 6, lane = t & 63;
    const int wm   = (wave & 1) * 16;
    const int wn   = (wave >> 1) * 128;
    const int lm   = lane & 15;
    const int chkg = lane >> 4;
    const int rq   = chkg * 4;
    const bool hasA = (wave & 1) == 0;

    const short* bSp[4]; short* bDp[4];
    #pragma unroll
    for (int i = 0; i < 4; ++i) {
        const int c   = wave * 4 + i;
        const int row = c * 16 + (lane >> 2);
        const int xc  = (lane & 3) ^ swz(row);
        bSp[i] = Wt + (long)row * KSTR + xc * 8;
        bDp[i] = Bs + c * 512;
    }
    const short* aSp = nullptr; short* aDp = nullptr;
    if (hasA) {
        const int c   = wave >> 1;
        const int row = c * 16 + (lane >> 2);
        const int xc  = (lane & 3) ^ swz(row);
        aSp = A + (long)(m0 + row) * KSTR + xc * 8;
        aDp = As + c * 512;
    }

    const int offA = (wm + lm) * 32 + (chkg ^ swz(wm + lm)) * 8;
    int offB[8];
    #pragma unroll
    for (int u = 0; u < 8; ++u) {
        const int r = wn + u * 16 + lm;
        offB[u] = r * 32 + (chkg ^ swz(r)) * 8;
    }

    f32x4 acc[8] = {};

#define STGP(BUF, KT) do {                                            \
        const int _ko = (KT) * 32;                                    \
        if (hasA) gload16(aSp + _ko, aDp + (BUF) * 1024);             \
        gload16(bSp[0] + _ko, bDp[0] + (BUF) * 8192);                 \
        gload16(bSp[1] + _ko, bDp[1] + (BUF) * 8192);                 \
        gload16(bSp[2] + _ko, bDp[2] + (BUF) * 8192);                 \
        gload16(bSp[3] + _ko, bDp[3] + (BUF) * 8192);                 \
    } while (0)

#define GBP(T, BUF, WA, WB, DOSTAGE) do {                             \
        if (hasA) vmwait<WA>(); else vmwait<WB>();                    \
        __builtin_amdgcn_s_barrier();                                 \
        bf16x8 af = *(const bf16x8*)(As + (BUF) * 1024 + offA);       \
        bf16x8 bv[8];                                                 \
        _Pragma("unroll")                                             \
        for (int u = 0; u < 8; ++u)                                   \
            bv[u] = *(const bf16x8*)(Bs + (BUF) * 8192 + offB[u]);    \
        asm volatile("s_waitcnt lgkmcnt(0)" ::: "memory");            \
        __builtin_amdgcn_s_barrier();                                 \
        __builtin_amdgcn_sched_barrier(0);                            \
        if (DOSTAGE) STGP(BUF, (T) + 2);                              \
        _Pragma("unroll")                                             \
        for (int u = 0; u < 8; ++u)                                   \
            acc[u] = MFMA16(af, bv[u], acc[u], 0, 0, 0);              \
    } while (0)

    STGP(0, 0);
    STGP(1, 1);
    for (int tt = 0; tt < NT - 2; tt += 2) {
        GBP(tt,     0, 5, 4, true);
        GBP(tt + 1, 1, 5, 4, true);
    }
    GBP(NT - 2, 0, 5, 4, false);
    GBP(NT - 1, 1, 0, 0, false);
#undef GBP
#undef STGP

    #pragma unroll
    for (int u = 0; u < 8; ++u) {
        const int gn = wn + u * 16 + lm;
        #pragma unroll
        for (int r = 0; r < 4; ++r)
            Pout[(long)(m0 + wm + rq + r) * DM + gn] = acc[u][r];
    }
}

// ---------------------------------------------------------------------------
// Split-K ln2, part 2: out = LN(resid + PART0 + PART1 + bl2). Streaming:
// 4 waves x 8 rows; lane owns 4 consecutive cols; 64-lane shfl row-reduce.
// ---------------------------------------------------------------------------
__global__ __launch_bounds__(256) void ln2_fin_k(
    const float* __restrict__ PART, const short* __restrict__ residb,
    const float* __restrict__ bl2, const float* __restrict__ g,
    const float* __restrict__ be, short* __restrict__ outb,
    short* __restrict__ outq, float* __restrict__ outf,
    const float* __restrict__ pos)
{
    const int wave = threadIdx.x >> 6, lane = threadIdx.x & 63;
    const int c0 = lane * 4;
    const f32x4 bb = *(const f32x4*)(bl2 + c0);
    const f32x4 gg = *(const f32x4*)(g + c0);
    const f32x4 ee = *(const f32x4*)(be + c0);
    #pragma unroll 1
    for (int r = 0; r < 8; ++r) {
        const long row = (long)blockIdx.x * 32 + wave * 8 + r;
        const f32x4 p0 = *(const f32x4*)(PART + row * DM + c0);
        const f32x4 p1 = *(const f32x4*)(PART + (long)MROWS * DM + row * DM + c0);
        const bf16x4 rr = *(const bf16x4*)(residb + row * DM + c0);
        float v[4]; float s = 0.f, s2 = 0.f;
        #pragma unroll
        for (int j = 0; j < 4; ++j) {
            v[j] = p0[j] + p1[j] + bb[j] + bf2f(rr[j]);
            s += v[j]; s2 += v[j] * v[j];
        }
        #pragma unroll
        for (int o = 1; o < 64; o <<= 1) {
            s  += __shfl_xor(s,  o, 64);
            s2 += __shfl_xor(s2, o, 64);
        }
        const float mean = s * (1.f / DM);
        const float var  = s2 * (1.f / DM) - mean * mean;
        const float rstd = rsqrtf(var + 1e-5f);
        float o4[4];
        #pragma unroll
        for (int j = 0; j < 4; ++j)
            o4[j] = (v[j] - mean) * rstd * gg[j] + ee[j];
        if (outb) {
            bf16x4 ob;
            #pragma unroll
            for (int j = 0; j < 4; ++j) ob[j] = f2bf(o4[j]);
            *(bf16x4*)(outb + row * DM + c0) = ob;
        }
        if (outq) {
            const f32x4 pp = *(const f32x4*)(pos + row * DM + c0);
            bf16x4 oq;
            #pragma unroll
            for (int j = 0; j < 4; ++j) oq[j] = f2bf(o4[j] + pp[j]);
            *(bf16x4*)(outq + row * DM + c0) = oq;
        }
        if (outf) {
            f32x4 of;
            #pragma unroll
            for (int j = 0; j < 4; ++j) of[j] = o4[j];
            *(f32x4*)(outf + row * DM + c0) = of;
        }
    }
}

// ---------------------------------------------------------------------------
// Deformable attention sampling v3 (unchanged, grid 2720).
// ---------------------------------------------------------------------------
__global__ __launch_bounds__(256) void deform_attn_v3(
    const short* __restrict__ Vb,    // (NB*NH, LEN, 32) bf16
    const float* __restrict__ OFF,   // (MROWS, 256)
    const float* __restrict__ AW,    // (MROWS, 128)
    const float* __restrict__ vr,    // (NB, NLV, 2)
    bf16x4* __restrict__ ATTb)       // (MROWS, 64) bf16x4
{
    const int starts[5] = {0, 4096, 5120, 5376, 5440};
    const int dims[4]   = {64, 32, 16, 8};

    const int wave = threadIdx.x >> 6;
    const int lane = threadIdx.x & 63;
    const int h    = lane >> 3;
    const int d4   = lane & 7;

    const int gq = blockIdx.x * 4 + wave;
    const int n  = gq / LEN;
    const int q  = gq % LEN;

    int lq = 3;
    if (q < 4096) lq = 0; else if (q < 5120) lq = 1; else if (q < 5376) lq = 2;
    const int r  = q - starts[lq];
    const int Wq = dims[lq];
    const int gy = r / Wq, gx = r % Wq;
    const float vrxq = vr[(n * NLV + lq) * 2 + 0];
    const float vryq = vr[(n * NLV + lq) * 2 + 1];
    const float rx = (gx + 0.5f) / (vrxq * Wq);
    const float ry = (gy + 0.5f) / (vryq * Wq);

    const long row = (long)n * LEN + q;

    const float* awp = AW + row * 128 + h * 16;
    float a[16];
    float mx = -1e30f;
    #pragma unroll
    for (int i = 0; i < 16; ++i) { a[i] = awp[i]; mx = fmaxf(mx, a[i]); }
    float s = 0.f;
    #pragma unroll
    for (int i = 0; i < 16; ++i) { a[i] = __expf(a[i] - mx); s += a[i]; }
    const float inv = 1.f / s;

    const float* offp = OFF + row * 256 + h * 32;

    float4 acc = {0.f, 0.f, 0.f, 0.f};
    #pragma unroll
    for (int lvl = 0; lvl < NLV; ++lvl) {
        const int Hl = dims[lvl];
        const int Wl = Hl;
        const float fW = (float)Wl;
        const int sb = starts[lvl];
        const float lx = rx * vr[(n * NLV + lvl) * 2 + 0];
        const float ly = ry * vr[(n * NLV + lvl) * 2 + 1];
        const short* vb = Vb + ((long)(n * NH + h) * LEN + sb) * 32 + d4 * 4;
        #pragma unroll
        for (int p = 0; p < NPT; ++p) {
            const float ox = offp[lvl * 8 + p * 2 + 0];
            const float oy = offp[lvl * 8 + p * 2 + 1];
            const float x = fmaf(lx, fW, ox) - 0.5f;
            const float y = fmaf(ly, fW, oy) - 0.5f;
            const float x0f = floorf(x), y0f = floorf(y);
            const int ix0 = (int)x0f, iy0 = (int)y0f;
            const float wx1 = x - x0f, wy1 = y - y0f;
            const float wx0 = 1.f - wx1, wy0 = 1.f - wy1;

            const bool vx0 = (ix0 >= 0)     && (ix0 < Wl);
            const bool vx1 = (ix0 + 1 >= 0) && (ix0 + 1 < Wl);
            const bool vy0 = (iy0 >= 0)     && (iy0 < Hl);
            const bool vy1 = (iy0 + 1 >= 0) && (iy0 + 1 < Hl);
            const int cx0 = min(max(ix0, 0), Wl - 1);
            const int cx1 = min(max(ix0 + 1, 0), Wl - 1);
            const int cy0 = min(max(iy0, 0), Hl - 1);
            const int cy1 = min(max(iy0 + 1, 0), Hl - 1);

            const float w00 = (vx0 && vy0) ? wx0 * wy0 : 0.f;
            const float w10 = (vx1 && vy0) ? wx1 * wy0 : 0.f;
            const float w01 = (vx0 && vy1) ? wx0 * wy1 : 0.f;
            const float w11 = (vx1 && vy1) ? wx1 * wy1 : 0.f;

            const bf16x4 g00 = *(const bf16x4*)(vb + (long)(cy0 * Wl + cx0) * 32);
            const bf16x4 g10 = *(const bf16x4*)(vb + (long)(cy0 * Wl + cx1) * 32);
            const bf16x4 g01 = *(const bf16x4*)(vb + (long)(cy1 * Wl + cx0) * 32);
            const bf16x4 g11 = *(const bf16x4*)(vb + (long)(cy1 * Wl + cx1) * 32);

            const float awv = a[lvl * 4 + p] * inv;
            #pragma unroll
            for (int e = 0; e < 4; ++e) {
                float sv = w00 * bf2f(g00[e]) + w10 * bf2f(g10[e])
                         + w01 * bf2f(g01[e]) + w11 * bf2f(g11[e]);
                (&acc.x)[e] += awv * sv;
            }
        }
    }
    bf16x4 ob;
    ob[0] = f2bf(acc.x); ob[1] = f2bf(acc.y);
    ob[2] = f2bf(acc.z); ob[3] = f2bf(acc.w);
    ATTb[row * 64 + h * 8 + d4] = ob;
}

// ---------------------------------------------------------------------------
extern "C" void kernel_launch(void* const* d_in, const int* in_sizes, int n_in,
                              void* d_out, int out_size, void* d_ws, size_t ws_size,
                              hipStream_t stream)
{
    const float* src = (const float*)d_in[0];
    const float* pos = (const float*)d_in[1];
    const float* vr  = (const float*)d_in[2];
    const float* Wv_   = (const float*)d_in[3];
    const float* bv_   = (const float*)d_in[4];
    const float* Woff_ = (const float*)d_in[5];
    const float* boff_ = (const float*)d_in[6];
    const float* Wa_   = (const float*)d_in[7];
    const float* ba_   = (const float*)d_in[8];
    const float* Wo_   = (const float*)d_in[9];
    const float* bo_   = (const float*)d_in[10];
    const float* g1_   = (const float*)d_in[11];
    const float* be1_  = (const float*)d_in[12];
    const float* Wl1_  = (const float*)d_in[13];
    const float* bl1_  = (const float*)d_in[14];
    const float* Wl2_  = (const float*)d_in[15];
    const float* bl2_  = (const float*)d_in[16];
    const float* g2_   = (const float*)d_in[17];
    const float* be2_  = (const float*)d_in[18];

    const long SZ = (long)MROWS * DM;        // 2,785,280 elements
    float* ws = (float*)d_ws;
    float* OFF  = ws;                         // f32 M x 256
    float* AW   = OFF + SZ;                   // f32 M x 128
    short* Vb   = (short*)(AW + (long)MROWS * 128);  // bf16 (NB*NH, LEN, 32)
    short* curb = Vb   + SZ;                  // bf16 M x 256 (trunk)
    short* qb   = curb + SZ;                  // bf16 M x 256 (trunk + pos)
    short* ATTb = qb   + SZ;                  // bf16 M x 256
    short* XAb  = ATTb + SZ;                  // bf16 M x 256 (LN1 out)
    short* FFNb = XAb  + SZ;                  // bf16 M x 1024
    short* Wt   = FFNb + (long)MROWS * DFFN;  // 2 x 753664 bf16 weights
    float* PART = (float*)(Wt + 2L * 753664); // f32 2 x M x 256 split-K partials

    const dim3 blk(256);
    const int GYM = MROWS / 128;              // 85
    const int GLN = MROWS / 32;               // 340

    hipLaunchKernelGGL(prep_all, dim3(1472 + SZ / 4 / 256), blk, 0, stream,
                       Wv_, Woff_, Wa_, Wo_, Wl1_, Wl2_, Wt,
                       (const float4*)src, (const float4*)pos,
                       (bf16x4*)curb, (bf16x4*)qb);

    for (int l = 0; l < 2; ++l) {
        const short* Wbase = Wt + (long)l * 753664;
        const float* bv   = bv_   + (long)l * DM;
        const float* boff = boff_ + (long)l * 256;
        const float* ba   = ba_   + (long)l * 128;
        const float* bo   = bo_   + (long)l * DM;
        const float* g1   = g1_   + (long)l * DM;
        const float* be1  = be1_  + (long)l * DM;
        const float* bl1  = bl1_  + (long)l * DFFN;
        const float* bl2  = bl2_  + (long)l * DM;
        const float* g2   = g2_   + (long)l * DM;
        const float* be2  = be2_  + (long)l * DM;

        // [Vb | OFF | AW] = [curb | qb] @ [Wv|Woff|Wa]   (BN=128, 5x85)
        hipLaunchKernelGGL(gemm_qkv128, dim3(5, GYM), blk, 0, stream,
                           curb, qb, Wbase, bv, boff, ba, Vb, OFF, AW);
        hipLaunchKernelGGL(deform_attn_v3, dim3(MROWS / 4), blk, 0, stream,
                           Vb, OFF, AW, vr, (bf16x4*)ATTb);
        // XAb = bf16( LN(curb + ATT@Wo + bo) )
        hipLaunchKernelGGL((gemm_ln<256>), dim3(GLN), blk, 0, stream,
                           ATTb, Wbase + 163840, bo, curb, g1, be1,
                           XAb, (short*)nullptr, (float*)nullptr,
                           (const float*)nullptr);
        // FFNb = relu(XAb @ Wl1 + bl1)  bf16 out  (BN=128, 8x85)
        hipLaunchKernelGGL((gemm128v2<1, 1, 256>), dim3(8, GYM), blk, 0, stream,
                           XAb, Wbase + 229376, bl1, (float*)nullptr, FFNb, 1024);
        // ln2 split-K: partials (2x340 blocks, K=512 each), then finisher
        hipLaunchKernelGGL((ln2_part_k<512, 1024>), dim3(2, GLN), blk, 0, stream,
                           FFNb, Wbase + 491520, PART);
        if (l == 0) {
            hipLaunchKernelGGL(ln2_fin_k, dim3(GLN), blk, 0, stream,
                               PART, XAb, bl2, g2, be2,
                               curb, qb, (float*)nullptr, pos);
        } else {
            hipLaunchKernelGGL(ln2_fin_k, dim3(GLN), blk, 0, stream,
                               PART, XAb, bl2, g2, be2,
                               (short*)nullptr, (short*)nullptr,
                               (float*)d_out, (const float*)nullptr);
        }
    }
}

// Round 6
// 287.598 us; speedup vs baseline: 4.8745x; 1.0216x over previous
//
#include <hip/hip_runtime.h>
#include <math.h>

#define LEN   5440
#define NB    2
#define MROWS (NB * LEN)   // 10880
#define DM    256
#define NH    8
#define HD    32
#define NLV   4
#define NPT   4
#define DFFN  1024

typedef __attribute__((ext_vector_type(8))) short bf16x8;
typedef __attribute__((ext_vector_type(4))) short bf16x4;
typedef __attribute__((ext_vector_type(4))) float f32x4;

#define MFMA16 __builtin_amdgcn_mfma_f32_16x16x32_bf16

__device__ __forceinline__ short f2bf(float f) {
    union { float f; unsigned u; } cv; cv.f = f;
    unsigned r = cv.u + 0x7fffu + ((cv.u >> 16) & 1u);   // RNE
    return (short)(r >> 16);
}
__device__ __forceinline__ float bf2f(short s) {
    union { unsigned u; float f; } cv;
    cv.u = ((unsigned)(unsigned short)s) << 16;
    return cv.f;
}

__device__ __forceinline__ void gload16(const short* g, short* l) {
    __builtin_amdgcn_global_load_lds(
        (__attribute__((address_space(1))) void*)g,
        (__attribute__((address_space(3))) void*)l, 16, 0, 0);
}

template <int N> __device__ __forceinline__ void vmwait();
template <> __device__ __forceinline__ void vmwait<0>() { asm volatile("s_waitcnt vmcnt(0)" ::: "memory"); }
template <> __device__ __forceinline__ void vmwait<8>() { asm volatile("s_waitcnt vmcnt(8)" ::: "memory"); }
template <> __device__ __forceinline__ void vmwait<9>() { asm volatile("s_waitcnt vmcnt(9)" ::: "memory"); }

// BK=64 rows are 128B = 8 x 16B chunks; phys_chunk = logical_chunk ^ (row&7).
// Involution applied on BOTH the staging source and the ds_read address.

// ---------------------------------------------------------------------------
// Merged one-shot prep (unchanged from R5).
// ---------------------------------------------------------------------------
__global__ __launch_bounds__(256) void prep_all(
    const float* __restrict__ Wv,  const float* __restrict__ Woff,
    const float* __restrict__ Wa,  const float* __restrict__ Wo,
    const float* __restrict__ Wl1, const float* __restrict__ Wl2,
    short* __restrict__ out,
    const float4* __restrict__ s4, const float4* __restrict__ p4,
    bf16x4* __restrict__ curb, bf16x4* __restrict__ qb)
{
    __shared__ short T[32][33];
    if (blockIdx.x >= 1472) {
        const int i = (blockIdx.x - 1472) * 256 + threadIdx.x;
        float4 s = s4[i], p = p4[i];
        bf16x4 c, q;
        c[0] = f2bf(s.x); c[1] = f2bf(s.y); c[2] = f2bf(s.z); c[3] = f2bf(s.w);
        q[0] = f2bf(s.x + p.x); q[1] = f2bf(s.y + p.y);
        q[2] = f2bf(s.z + p.z); q[3] = f2bf(s.w + p.w);
        curb[i] = c; qb[i] = q;
        return;
    }
    int bx = blockIdx.x;
    int l  = bx / 736;
    int t  = bx % 736;
    const float* src; int K, N; long doff;
    if      (t < 64)  { src = Wv;   K = 256;  N = 256;  doff = 0;      }
    else if (t < 128) { src = Woff; K = 256;  N = 256;  doff = 65536;  t -= 64;  }
    else if (t < 160) { src = Wa;   K = 256;  N = 128;  doff = 131072; t -= 128; }
    else if (t < 224) { src = Wo;   K = 256;  N = 256;  doff = 163840; t -= 160; }
    else if (t < 480) { src = Wl1;  K = 256;  N = 1024; doff = 229376; t -= 224; }
    else              { src = Wl2;  K = 1024; N = 256;  doff = 491520; t -= 480; }
    src += (long)l * K * N;
    short* dst = out + (long)l * 753664 + doff;

    const int ntx = N / 32;
    const int n0 = (t % ntx) * 32, k0 = (t / ntx) * 32;

    const int tid = threadIdx.x;
    {
        const int n = tid & 31, kq = tid >> 5;
        #pragma unroll
        for (int i = 0; i < 4; ++i) {
            int k = kq * 4 + i;
            T[n][k] = f2bf(src[(long)(k0 + k) * N + n0 + n]);
        }
    }
    __syncthreads();
    {
        const int k = tid & 31, nq = tid >> 5;
        #pragma unroll
        for (int i = 0; i < 4; ++i) {
            int n = nq * 4 + i;
            dst[(long)(n0 + n) * K + k0 + k] = T[n][k];
        }
    }
}

// ---------------------------------------------------------------------------
// MFMA bf16 GEMM core v3: 128x128 tile, BK=64 (half the K-step count of v2),
// global_load_lds 2-buffer counted-vmcnt staging, 8-chunk XOR swizzle.
// Per K-step: 8 gload16/thread, 16 ds_read_b128, 32 MFMA.
// OMODE: 0 f32 row-major, 1 bf16 row-major, 2 bf16 into V planes.
// ---------------------------------------------------------------------------
template <int RELU, int OMODE, int K>
__device__ __forceinline__ void gemm_core128_v3(
    short* As, short* Bs,
    const short* __restrict__ A, const short* __restrict__ Wt,
    const float* __restrict__ bias, float* __restrict__ Cf,
    short* __restrict__ Cb, int ldc, int m0, int wrow0, int ccol0)
{
    constexpr int NT = K / 64;
    static_assert(NT >= 4 && (NT & 1) == 0, "NT even >= 4");
    const int t    = threadIdx.x;
    const int wave = t >> 6, lane = t & 63;
    const int wm   = (wave & 1) * 64;
    const int wn   = (wave >> 1) * 64;
    const int lm   = lane & 15;
    const int chkg = lane >> 4;

    // staging: per matrix, wave w covers rows [w*32, w*32+32), 4 issues of
    // 8 rows x 8 chunks; source chunk pre-swizzled, LDS dest linear.
    const short* aS[4]; const short* bS[4];
    int ldst[4];
    #pragma unroll
    for (int j = 0; j < 4; ++j) {
        const int row = wave * 32 + j * 8 + (lane >> 3);
        const int sc  = (lane & 7) ^ (row & 7);
        aS[j] = A  + (long)(m0 + row) * K + sc * 8;
        bS[j] = Wt + (long)(wrow0 + row) * K + sc * 8;
        ldst[j] = wave * 2048 + j * 512;       // shorts, wave-uniform
    }

    // fragment read offsets (shorts), kk=0; kk=1 = offset ^ 32
    int offA[4], offB[4];
    #pragma unroll
    for (int s = 0; s < 4; ++s) {
        const int r = wm + s * 16 + lm;
        offA[s] = r * 64 + ((chkg ^ (r & 7)) * 8);
    }
    #pragma unroll
    for (int u = 0; u < 4; ++u) {
        const int r = wn + u * 16 + lm;
        offB[u] = r * 64 + ((chkg ^ (r & 7)) * 8);
    }

    f32x4 acc[4][4] = {};

#define STG3(BUF, KT) do {                                            \
        const int _ko = (KT) * 64;                                    \
        _Pragma("unroll")                                             \
        for (int j = 0; j < 4; ++j)                                   \
            gload16(aS[j] + _ko, As + (BUF) * 8192 + ldst[j]);        \
        _Pragma("unroll")                                             \
        for (int j = 0; j < 4; ++j)                                   \
            gload16(bS[j] + _ko, Bs + (BUF) * 8192 + ldst[j]);        \
    } while (0)

#define GB3(T, BUF, WN, DOSTAGE) do {                                 \
        vmwait<WN>();                                                 \
        __builtin_amdgcn_s_barrier();                                 \
        bf16x8 a0[4], a1[4], b0[4], b1[4];                            \
        _Pragma("unroll")                                             \
        for (int s = 0; s < 4; ++s) {                                 \
            a0[s] = *(const bf16x8*)(As + (BUF) * 8192 + offA[s]);    \
            a1[s] = *(const bf16x8*)(As + (BUF) * 8192 + (offA[s] ^ 32)); \
        }                                                             \
        _Pragma("unroll")                                             \
        for (int u = 0; u < 4; ++u) {                                 \
            b0[u] = *(const bf16x8*)(Bs + (BUF) * 8192 + offB[u]);    \
            b1[u] = *(const bf16x8*)(Bs + (BUF) * 8192 + (offB[u] ^ 32)); \
        }                                                             \
        asm volatile("s_waitcnt lgkmcnt(0)" ::: "memory");            \
        __builtin_amdgcn_s_barrier();                                 \
        __builtin_amdgcn_sched_barrier(0);                            \
        if (DOSTAGE) STG3(BUF, (T) + 2);                              \
        _Pragma("unroll")                                             \
        for (int s = 0; s < 4; ++s)                                   \
            _Pragma("unroll")                                         \
            for (int u = 0; u < 4; ++u) {                             \
                acc[s][u] = MFMA16(a0[s], b0[u], acc[s][u], 0, 0, 0); \
                acc[s][u] = MFMA16(a1[s], b1[u], acc[s][u], 0, 0, 0); \
            }                                                         \
    } while (0)

    STG3(0, 0);
    STG3(1, 1);
    for (int tt = 0; tt < NT - 2; tt += 2) {
        GB3(tt,     0, 8, true);
        GB3(tt + 1, 1, 8, true);
    }
    GB3(NT - 2, 0, 8, false);
    GB3(NT - 1, 1, 0, false);
#undef GB3
#undef STG3

    const int col = lane & 15;
    const int rq  = (lane >> 4) * 4;
    #pragma unroll
    for (int s = 0; s < 4; ++s) {
        #pragma unroll
        for (int u = 0; u < 4; ++u) {
            const int gn = ccol0 + wn + u * 16 + col;
            const float bb = bias[gn];
            #pragma unroll
            for (int r = 0; r < 4; ++r) {
                const int gm = m0 + wm + s * 16 + rq + r;
                float v = acc[s][u][r] + bb;
                if (RELU) v = fmaxf(v, 0.f);
                if (OMODE == 0) {
                    Cf[(long)gm * ldc + gn] = v;
                } else if (OMODE == 1) {
                    Cb[(long)gm * ldc + gn] = f2bf(v);
                } else {
                    const int n   = gm / LEN;
                    const int pix = gm - n * LEN;
                    const int h   = gn >> 5, d = gn & 31;
                    Cb[((long)(n * NH + h) * LEN + pix) * 32 + d] = f2bf(v);
                }
            }
        }
    }
}

template <int RELU, int OMODE, int K>
__global__ __launch_bounds__(256) void gemm128v3(
    const short* __restrict__ A, const short* __restrict__ Wt,
    const float* __restrict__ bias, float* Cf, short* Cb, int ldc)
{
    __shared__ __align__(16) short As[2 * 128 * 64];
    __shared__ __align__(16) short Bs[2 * 128 * 64];
    gemm_core128_v3<RELU, OMODE, K>(As, Bs, A, Wt, bias, Cf, Cb, ldc,
                                    blockIdx.y * 128, blockIdx.x * 128,
                                    blockIdx.x * 128);
}

// Fused query-side GEMM: [Vb | OFF | AW] over N=640.
__global__ __launch_bounds__(256) void gemm_qkv128(
    const short* __restrict__ curb, const short* __restrict__ qb,
    const short* __restrict__ Wt, const float* __restrict__ bv,
    const float* __restrict__ boff, const float* __restrict__ ba,
    short* __restrict__ Vb, float* __restrict__ OFF, float* __restrict__ AW)
{
    __shared__ __align__(16) short As[2 * 128 * 64];
    __shared__ __align__(16) short Bs[2 * 128 * 64];
    const int n0 = blockIdx.x * 128;   // 0,128,256,384,512
    if (n0 < 256) {
        gemm_core128_v3<0, 2, 256>(As, Bs, curb, Wt, bv, (float*)nullptr, Vb,
                                   256, blockIdx.y * 128, n0, n0);
    } else if (n0 < 512) {
        gemm_core128_v3<0, 0, 256>(As, Bs, qb, Wt, boff, OFF, (short*)nullptr,
                                   256, blockIdx.y * 128, n0, n0 - 256);
    } else {
        gemm_core128_v3<0, 0, 256>(As, Bs, qb, Wt, ba, AW, (short*)nullptr,
                                   128, blockIdx.y * 128, n0, n0 - 512);
    }
}

// ---------------------------------------------------------------------------
// Fused GEMM + residual(bf16) + LayerNorm, M32 tile, N=256, BK=64.
// All 4 waves stage A (1 issue) + B (8 issues); counted vmwait<9>.
// ---------------------------------------------------------------------------
template <int K>
__global__ __launch_bounds__(256) void gemm_ln(
    const short* __restrict__ A, const short* __restrict__ Wt,
    const float* __restrict__ bias, const short* __restrict__ residb,
    const float* __restrict__ g, const float* __restrict__ be,
    short* __restrict__ outb, short* __restrict__ outq,
    float* __restrict__ outf, const float* __restrict__ pos)
{
    constexpr int NT = K / 64;
    static_assert(NT >= 4 && (NT & 1) == 0, "NT even >= 4");
    __shared__ __align__(16) short As[2 * 32 * 64];    // 2 x 2048
    __shared__ __align__(16) short Bs[2 * 256 * 64];   // 2 x 16384
    __shared__ float red[2][32][2];

    const int t    = threadIdx.x;
    const int wave = t >> 6, lane = t & 63;
    const int wm   = (wave & 1) * 16;
    const int wn   = (wave >> 1) * 128;
    const int lm   = lane & 15;
    const int chkg = lane >> 4;
    const int rq   = chkg * 4;
    const int m0   = blockIdx.x * 32;

    // resid prefetch FIRST (oldest vmcnt events)
    short rr[8][4];
    #pragma unroll
    for (int u = 0; u < 8; ++u)
        #pragma unroll
        for (int r = 0; r < 4; ++r)
            rr[u][r] = residb[(long)(m0 + wm + rq + r) * DM + wn + u * 16 + lm];
    asm volatile("" ::: "memory");

    // staging: A = 1 issue (block-wide 32 rows x 8 chunks), B = 8 issues
    const int arow = t >> 3;
    const short* aSp = A + (long)(m0 + arow) * K + (((t & 7) ^ (arow & 7)) * 8);
    const int aDst = wave * 512;
    const short* bSp[8]; int bDst[8];
    #pragma unroll
    for (int j = 0; j < 8; ++j) {
        const int row = wave * 64 + j * 8 + (lane >> 3);
        const int sc  = (lane & 7) ^ (row & 7);
        bSp[j] = Wt + (long)row * K + sc * 8;
        bDst[j] = wave * 4096 + j * 512;
    }

    const int offA = (wm + lm) * 64 + ((chkg ^ ((wm + lm) & 7)) * 8);
    int offB[8];
    #pragma unroll
    for (int u = 0; u < 8; ++u) {
        const int r = wn + u * 16 + lm;
        offB[u] = r * 64 + ((chkg ^ (r & 7)) * 8);
    }

    f32x4 acc[8] = {};

#define STGL(BUF, KT) do {                                            \
        const int _ko = (KT) * 64;                                    \
        gload16(aSp + _ko, As + (BUF) * 2048 + aDst);                 \
        _Pragma("unroll")                                             \
        for (int j = 0; j < 8; ++j)                                   \
            gload16(bSp[j] + _ko, Bs + (BUF) * 16384 + bDst[j]);      \
    } while (0)

#define GBLN(T, BUF, WN, DOSTAGE) do {                                \
        vmwait<WN>();                                                 \
        __builtin_amdgcn_s_barrier();                                 \
        bf16x8 af0 = *(const bf16x8*)(As + (BUF) * 2048 + offA);      \
        bf16x8 af1 = *(const bf16x8*)(As + (BUF) * 2048 + (offA ^ 32)); \
        bf16x8 b0[8], b1[8];                                          \
        _Pragma("unroll")                                             \
        for (int u = 0; u < 8; ++u) {                                 \
            b0[u] = *(const bf16x8*)(Bs + (BUF) * 16384 + offB[u]);   \
            b1[u] = *(const bf16x8*)(Bs + (BUF) * 16384 + (offB[u] ^ 32)); \
        }                                                             \
        asm volatile("s_waitcnt lgkmcnt(0)" ::: "memory");            \
        __builtin_amdgcn_s_barrier();                                 \
        __builtin_amdgcn_sched_barrier(0);                            \
        if (DOSTAGE) STGL(BUF, (T) + 2);                              \
        _Pragma("unroll")                                             \
        for (int u = 0; u < 8; ++u) {                                 \
            acc[u] = MFMA16(af0, b0[u], acc[u], 0, 0, 0);             \
            acc[u] = MFMA16(af1, b1[u], acc[u], 0, 0, 0);             \
        }                                                             \
    } while (0)

    STGL(0, 0);
    STGL(1, 1);
    for (int tt = 0; tt < NT - 2; tt += 2) {
        GBLN(tt,     0, 9, true);
        GBLN(tt + 1, 1, 9, true);
    }
    GBLN(NT - 2, 0, 9, false);
    GBLN(NT - 1, 1, 0, false);
#undef GBLN
#undef STGL

    #pragma unroll
    for (int u = 0; u < 8; ++u) {
        const int gn = wn + u * 16 + lm;
        const float bb = bias[gn];
        #pragma unroll
        for (int r = 0; r < 4; ++r)
            acc[u][r] += bb + bf2f(rr[u][r]);
    }

    float rs[4], r2[4];
    #pragma unroll
    for (int r = 0; r < 4; ++r) {
        float s = 0.f, s2 = 0.f;
        #pragma unroll
        for (int u = 0; u < 8; ++u) { const float v = acc[u][r]; s += v; s2 += v * v; }
        rs[r] = s; r2[r] = s2;
    }
    #pragma unroll
    for (int o = 1; o < 16; o <<= 1)
        #pragma unroll
        for (int r = 0; r < 4; ++r) {
            rs[r] += __shfl_xor(rs[r], o, 64);
            r2[r] += __shfl_xor(r2[r], o, 64);
        }
    if (lm == 0) {
        #pragma unroll
        for (int r = 0; r < 4; ++r) {
            red[wave >> 1][wm + rq + r][0] = rs[r];
            red[wave >> 1][wm + rq + r][1] = r2[r];
        }
    }
    __syncthreads();
    #pragma unroll
    for (int r = 0; r < 4; ++r) {
        const int row = wm + rq + r;
        const float ts = red[0][row][0] + red[1][row][0];
        const float t2 = red[0][row][1] + red[1][row][1];
        const float mean = ts * (1.f / DM);
        const float var  = t2 * (1.f / DM) - mean * mean;
        rs[r] = mean;
        r2[r] = rsqrtf(var + 1e-5f);
    }
    #pragma unroll
    for (int u = 0; u < 8; ++u) {
        const int gn = wn + u * 16 + lm;
        const float gg = g[gn], bbe = be[gn];
        #pragma unroll
        for (int r = 0; r < 4; ++r) {
            const long gm = m0 + wm + rq + r;
            const float o = (acc[u][r] - rs[r]) * r2[r] * gg + bbe;
            if (outb) outb[gm * DM + gn] = f2bf(o);
            if (outq) outq[gm * DM + gn] = f2bf(o + pos[gm * DM + gn]);
            if (outf) outf[gm * DM + gn] = o;
        }
    }
}

// ---------------------------------------------------------------------------
// Split-K ln2 part 1, BK=64: PART[kk] = FFNb[:,kk*512:+512] @ Wl2t-slice.
// M32xN256, grid (2,340). KSTR = full row stride; caller offsets A/Wt by slice.
// ---------------------------------------------------------------------------
template <int KLEN, int KSTR>
__global__ __launch_bounds__(256) void ln2_part_k(
    const short* __restrict__ A0, const short* __restrict__ Wt0,
    float* __restrict__ PART)
{
    constexpr int NT = KLEN / 64;
    static_assert(NT >= 4 && (NT & 1) == 0, "NT even >= 4");
    __shared__ __align__(16) short As[2 * 32 * 64];
    __shared__ __align__(16) short Bs[2 * 256 * 64];

    const int kk = blockIdx.x;
    const int m0 = blockIdx.y * 32;
    const short* A  = A0  + kk * KLEN;
    const short* Wt = Wt0 + kk * KLEN;
    float* Pout = PART + (long)kk * MROWS * DM;

    const int t    = threadIdx.x;
    const int wave = t >> 6, lane = t & 63;
    const int wm   = (wave & 1) * 16;
    const int wn   = (wave >> 1) * 128;
    const int lm   = lane & 15;
    const int chkg = lane >> 4;
    const int rq   = chkg * 4;

    const int arow = t >> 3;
    const short* aSp = A + (long)(m0 + arow) * KSTR + (((t & 7) ^ (arow & 7)) * 8);
    const int aDst = wave * 512;
    const short* bSp[8]; int bDst[8];
    #pragma unroll
    for (int j = 0; j < 8; ++j) {
        const int row = wave * 64 + j * 8 + (lane >> 3);
        const int sc  = (lane & 7) ^ (row & 7);
        bSp[j] = Wt + (long)row * KSTR + sc * 8;
        bDst[j] = wave * 4096 + j * 512;
    }

    const int offA = (wm + lm) * 64 + ((chkg ^ ((wm + lm) & 7)) * 8);
    int offB[8];
    #pragma unroll
    for (int u = 0; u < 8; ++u) {
        const int r = wn + u * 16 + lm;
        offB[u] = r * 64 + ((chkg ^ (r & 7)) * 8);
    }

    f32x4 acc[8] = {};

#define STGP(BUF, KT) do {                                            \
        const int _ko = (KT) * 64;                                    \
        gload16(aSp + _ko, As + (BUF) * 2048 + aDst);                 \
        _Pragma("unroll")                                             \
        for (int j = 0; j < 8; ++j)                                   \
            gload16(bSp[j] + _ko, Bs + (BUF) * 16384 + bDst[j]);      \
    } while (0)

#define GBP(T, BUF, WN, DOSTAGE) do {                                 \
        vmwait<WN>();                                                 \
        __builtin_amdgcn_s_barrier();                                 \
        bf16x8 af0 = *(const bf16x8*)(As + (BUF) * 2048 + offA);      \
        bf16x8 af1 = *(const bf16x8*)(As + (BUF) * 2048 + (offA ^ 32)); \
        bf16x8 b0[8], b1[8];                                          \
        _Pragma("unroll")                                             \
        for (int u = 0; u < 8; ++u) {                                 \
            b0[u] = *(const bf16x8*)(Bs + (BUF) * 16384 + offB[u]);   \
            b1[u] = *(const bf16x8*)(Bs + (BUF) * 16384 + (offB[u] ^ 32)); \
        }                                                             \
        asm volatile("s_waitcnt lgkmcnt(0)" ::: "memory");            \
        __builtin_amdgcn_s_barrier();                                 \
        __builtin_amdgcn_sched_barrier(0);                            \
        if (DOSTAGE) STGP(BUF, (T) + 2);                              \
        _Pragma("unroll")                                             \
        for (int u = 0; u < 8; ++u) {                                 \
            acc[u] = MFMA16(af0, b0[u], acc[u], 0, 0, 0);             \
            acc[u] = MFMA16(af1, b1[u], acc[u], 0, 0, 0);             \
        }                                                             \
    } while (0)

    STGP(0, 0);
    STGP(1, 1);
    for (int tt = 0; tt < NT - 2; tt += 2) {
        GBP(tt,     0, 9, true);
        GBP(tt + 1, 1, 9, true);
    }
    GBP(NT - 2, 0, 9, false);
    GBP(NT - 1, 1, 0, false);
#undef GBP
#undef STGP

    #pragma unroll
    for (int u = 0; u < 8; ++u) {
        const int gn = wn + u * 16 + lm;
        #pragma unroll
        for (int r = 0; r < 4; ++r)
            Pout[(long)(m0 + wm + rq + r) * DM + gn] = acc[u][r];
    }
}

// ---------------------------------------------------------------------------
// Split-K ln2 part 2 (unchanged from R5).
// ---------------------------------------------------------------------------
__global__ __launch_bounds__(256) void ln2_fin_k(
    const float* __restrict__ PART, const short* __restrict__ residb,
    const float* __restrict__ bl2, const float* __restrict__ g,
    const float* __restrict__ be, short* __restrict__ outb,
    short* __restrict__ outq, float* __restrict__ outf,
    const float* __restrict__ pos)
{
    const int wave = threadIdx.x >> 6, lane = threadIdx.x & 63;
    const int c0 = lane * 4;
    const f32x4 bb = *(const f32x4*)(bl2 + c0);
    const f32x4 gg = *(const f32x4*)(g + c0);
    const f32x4 ee = *(const f32x4*)(be + c0);
    #pragma unroll 1
    for (int r = 0; r < 8; ++r) {
        const long row = (long)blockIdx.x * 32 + wave * 8 + r;
        const f32x4 p0 = *(const f32x4*)(PART + row * DM + c0);
        const f32x4 p1 = *(const f32x4*)(PART + (long)MROWS * DM + row * DM + c0);
        const bf16x4 rr = *(const bf16x4*)(residb + row * DM + c0);
        float v[4]; float s = 0.f, s2 = 0.f;
        #pragma unroll
        for (int j = 0; j < 4; ++j) {
            v[j] = p0[j] + p1[j] + bb[j] + bf2f(rr[j]);
            s += v[j]; s2 += v[j] * v[j];
        }
        #pragma unroll
        for (int o = 1; o < 64; o <<= 1) {
            s  += __shfl_xor(s,  o, 64);
            s2 += __shfl_xor(s2, o, 64);
        }
        const float mean = s * (1.f / DM);
        const float var  = s2 * (1.f / DM) - mean * mean;
        const float rstd = rsqrtf(var + 1e-5f);
        float o4[4];
        #pragma unroll
        for (int j = 0; j < 4; ++j)
            o4[j] = (v[j] - mean) * rstd * gg[j] + ee[j];
        if (outb) {
            bf16x4 ob;
            #pragma unroll
            for (int j = 0; j < 4; ++j) ob[j] = f2bf(o4[j]);
            *(bf16x4*)(outb + row * DM + c0) = ob;
        }
        if (outq) {
            const f32x4 pp = *(const f32x4*)(pos + row * DM + c0);
            bf16x4 oq;
            #pragma unroll
            for (int j = 0; j < 4; ++j) oq[j] = f2bf(o4[j] + pp[j]);
            *(bf16x4*)(outq + row * DM + c0) = oq;
        }
        if (outf) {
            f32x4 of;
            #pragma unroll
            for (int j = 0; j < 4; ++j) of[j] = o4[j];
            *(f32x4*)(outf + row * DM + c0) = of;
        }
    }
}

// ---------------------------------------------------------------------------
// Deformable attention sampling v3 (unchanged, grid 2720).
// ---------------------------------------------------------------------------
__global__ __launch_bounds__(256) void deform_attn_v3(
    const short* __restrict__ Vb,    // (NB*NH, LEN, 32) bf16
    const float* __restrict__ OFF,   // (MROWS, 256)
    const float* __restrict__ AW,    // (MROWS, 128)
    const float* __restrict__ vr,    // (NB, NLV, 2)
    bf16x4* __restrict__ ATTb)       // (MROWS, 64) bf16x4
{
    const int starts[5] = {0, 4096, 5120, 5376, 5440};
    const int dims[4]   = {64, 32, 16, 8};

    const int wave = threadIdx.x >> 6;
    const int lane = threadIdx.x & 63;
    const int h    = lane >> 3;
    const int d4   = lane & 7;

    const int gq = blockIdx.x * 4 + wave;
    const int n  = gq / LEN;
    const int q  = gq % LEN;

    int lq = 3;
    if (q < 4096) lq = 0; else if (q < 5120) lq = 1; else if (q < 5376) lq = 2;
    const int r  = q - starts[lq];
    const int Wq = dims[lq];
    const int gy = r / Wq, gx = r % Wq;
    const float vrxq = vr[(n * NLV + lq) * 2 + 0];
    const float vryq = vr[(n * NLV + lq) * 2 + 1];
    const float rx = (gx + 0.5f) / (vrxq * Wq);
    const float ry = (gy + 0.5f) / (vryq * Wq);

    const long row = (long)n * LEN + q;

    const float* awp = AW + row * 128 + h * 16;
    float a[16];
    float mx = -1e30f;
    #pragma unroll
    for (int i = 0; i < 16; ++i) { a[i] = awp[i]; mx = fmaxf(mx, a[i]); }
    float s = 0.f;
    #pragma unroll
    for (int i = 0; i < 16; ++i) { a[i] = __expf(a[i] - mx); s += a[i]; }
    const float inv = 1.f / s;

    const float* offp = OFF + row * 256 + h * 32;

    float4 acc = {0.f, 0.f, 0.f, 0.f};
    #pragma unroll
    for (int lvl = 0; lvl < NLV; ++lvl) {
        const int Hl = dims[lvl];
        const int Wl = Hl;
        const float fW = (float)Wl;
        const int sb = starts[lvl];
        const float lx = rx * vr[(n * NLV + lvl) * 2 + 0];
        const float ly = ry * vr[(n * NLV + lvl) * 2 + 1];
        const short* vb = Vb + ((long)(n * NH + h) * LEN + sb) * 32 + d4 * 4;
        #pragma unroll
        for (int p = 0; p < NPT; ++p) {
            const float ox = offp[lvl * 8 + p * 2 + 0];
            const float oy = offp[lvl * 8 + p * 2 + 1];
            const float x = fmaf(lx, fW, ox) - 0.5f;
            const float y = fmaf(ly, fW, oy) - 0.5f;
            const float x0f = floorf(x), y0f = floorf(y);
            const int ix0 = (int)x0f, iy0 = (int)y0f;
            const float wx1 = x - x0f, wy1 = y - y0f;
            const float wx0 = 1.f - wx1, wy0 = 1.f - wy1;

            const bool vx0 = (ix0 >= 0)     && (ix0 < Wl);
            const bool vx1 = (ix0 + 1 >= 0) && (ix0 + 1 < Wl);
            const bool vy0 = (iy0 >= 0)     && (iy0 < Hl);
            const bool vy1 = (iy0 + 1 >= 0) && (iy0 + 1 < Hl);
            const int cx0 = min(max(ix0, 0), Wl - 1);
            const int cx1 = min(max(ix0 + 1, 0), Wl - 1);
            const int cy0 = min(max(iy0, 0), Hl - 1);
            const int cy1 = min(max(iy0 + 1, 0), Hl - 1);

            const float w00 = (vx0 && vy0) ? wx0 * wy0 : 0.f;
            const float w10 = (vx1 && vy0) ? wx1 * wy0 : 0.f;
            const float w01 = (vx0 && vy1) ? wx0 * wy1 : 0.f;
            const float w11 = (vx1 && vy1) ? wx1 * wy1 : 0.f;

            const bf16x4 g00 = *(const bf16x4*)(vb + (long)(cy0 * Wl + cx0) * 32);
            const bf16x4 g10 = *(const bf16x4*)(vb + (long)(cy0 * Wl + cx1) * 32);
            const bf16x4 g01 = *(const bf16x4*)(vb + (long)(cy1 * Wl + cx0) * 32);
            const bf16x4 g11 = *(const bf16x4*)(vb + (long)(cy1 * Wl + cx1) * 32);

            const float awv = a[lvl * 4 + p] * inv;
            #pragma unroll
            for (int e = 0; e < 4; ++e) {
                float sv = w00 * bf2f(g00[e]) + w10 * bf2f(g10[e])
                         + w01 * bf2f(g01[e]) + w11 * bf2f(g11[e]);
                (&acc.x)[e] += awv * sv;
            }
        }
    }
    bf16x4 ob;
    ob[0] = f2bf(acc.x); ob[1] = f2bf(acc.y);
    ob[2] = f2bf(acc.z); ob[3] = f2bf(acc.w);
    ATTb[row * 64 + h * 8 + d4] = ob;
}

// ---------------------------------------------------------------------------
extern "C" void kernel_launch(void* const* d_in, const int* in_sizes, int n_in,
                              void* d_out, int out_size, void* d_ws, size_t ws_size,
                              hipStream_t stream)
{
    const float* src = (const float*)d_in[0];
    const float* pos = (const float*)d_in[1];
    const float* vr  = (const float*)d_in[2];
    const float* Wv_   = (const float*)d_in[3];
    const float* bv_   = (const float*)d_in[4];
    const float* Woff_ = (const float*)d_in[5];
    const float* boff_ = (const float*)d_in[6];
    const float* Wa_   = (const float*)d_in[7];
    const float* ba_   = (const float*)d_in[8];
    const float* Wo_   = (const float*)d_in[9];
    const float* bo_   = (const float*)d_in[10];
    const float* g1_   = (const float*)d_in[11];
    const float* be1_  = (const float*)d_in[12];
    const float* Wl1_  = (const float*)d_in[13];
    const float* bl1_  = (const float*)d_in[14];
    const float* Wl2_  = (const float*)d_in[15];
    const float* bl2_  = (const float*)d_in[16];
    const float* g2_   = (const float*)d_in[17];
    const float* be2_  = (const float*)d_in[18];

    const long SZ = (long)MROWS * DM;        // 2,785,280 elements
    float* ws = (float*)d_ws;
    float* OFF  = ws;                         // f32 M x 256
    float* AW   = OFF + SZ;                   // f32 M x 128
    short* Vb   = (short*)(AW + (long)MROWS * 128);  // bf16 (NB*NH, LEN, 32)
    short* curb = Vb   + SZ;                  // bf16 M x 256 (trunk)
    short* qb   = curb + SZ;                  // bf16 M x 256 (trunk + pos)
    short* ATTb = qb   + SZ;                  // bf16 M x 256
    short* XAb  = ATTb + SZ;                  // bf16 M x 256 (LN1 out)
    short* FFNb = XAb  + SZ;                  // bf16 M x 1024
    short* Wt   = FFNb + (long)MROWS * DFFN;  // 2 x 753664 bf16 weights
    float* PART = (float*)(Wt + 2L * 753664); // f32 2 x M x 256 partials

    const dim3 blk(256);
    const int GYM = MROWS / 128;              // 85
    const int GLN = MROWS / 32;               // 340

    hipLaunchKernelGGL(prep_all, dim3(1472 + SZ / 4 / 256), blk, 0, stream,
                       Wv_, Woff_, Wa_, Wo_, Wl1_, Wl2_, Wt,
                       (const float4*)src, (const float4*)pos,
                       (bf16x4*)curb, (bf16x4*)qb);

    for (int l = 0; l < 2; ++l) {
        const short* Wbase = Wt + (long)l * 753664;
        const float* bv   = bv_   + (long)l * DM;
        const float* boff = boff_ + (long)l * 256;
        const float* ba   = ba_   + (long)l * 128;
        const float* bo   = bo_   + (long)l * DM;
        const float* g1   = g1_   + (long)l * DM;
        const float* be1  = be1_  + (long)l * DM;
        const float* bl1  = bl1_  + (long)l * DFFN;
        const float* bl2  = bl2_  + (long)l * DM;
        const float* g2   = g2_   + (long)l * DM;
        const float* be2  = be2_  + (long)l * DM;

        // [Vb | OFF | AW] = [curb | qb] @ [Wv|Woff|Wa]   (BN=128, 5x85)
        hipLaunchKernelGGL(gemm_qkv128, dim3(5, GYM), blk, 0, stream,
                           curb, qb, Wbase, bv, boff, ba, Vb, OFF, AW);
        hipLaunchKernelGGL(deform_attn_v3, dim3(MROWS / 4), blk, 0, stream,
                           Vb, OFF, AW, vr, (bf16x4*)ATTb);
        // XAb = bf16( LN(curb + ATT@Wo + bo) )
        hipLaunchKernelGGL((gemm_ln<256>), dim3(GLN), blk, 0, stream,
                           ATTb, Wbase + 163840, bo, curb, g1, be1,
                           XAb, (short*)nullptr, (float*)nullptr,
                           (const float*)nullptr);
        // FFNb = relu(XAb @ Wl1 + bl1)  bf16 out  (BN=128, 8x85)
        hipLaunchKernelGGL((gemm128v3<1, 1, 256>), dim3(8, GYM), blk, 0, stream,
                           XAb, Wbase + 229376, bl1, (float*)nullptr, FFNb, 1024);
        // ln2 split-K: partials (2x340, K=512 each), then finisher
        hipLaunchKernelGGL((ln2_part_k<512, 1024>), dim3(2, GLN), blk, 0, stream,
                           FFNb, Wbase + 491520, PART);
        if (l == 0) {
            hipLaunchKernelGGL(ln2_fin_k, dim3(GLN), blk, 0, stream,
                               PART, XAb, bl2, g2, be2,
                               curb, qb, (float*)nullptr, pos);
        } else {
            hipLaunchKernelGGL(ln2_fin_k, dim3(GLN), blk, 0, stream,
                               PART, XAb, bl2, g2, be2,
                               (short*)nullptr, (short*)nullptr,
                               (float*)d_out, (const float*)nullptr);
        }
    }
}